// Round 8
// baseline (37.995 us; speedup 1.0000x reference)
//
#include <hip/hip_runtime.h>
#include <stdint.h>

#define SEQ  8192
#define NB   128
#define MAXP 4096
#define NT   512
#define RED  8                     // blocks per sequence: redundant chain, split emission
#define NCH  256                   // 32-wide chunks per sequence

__device__ __forceinline__ bool haszero8(uint64_t v) {
    return ((v - 0x0101010101010101ULL) & ~v & 0x8080808080808080ULL) != 0ULL;
}
__device__ __forceinline__ bool distinct8(uint64_t w) {
    uint64_t r1 = (w >> 8)  | (w << 56);
    uint64_t r2 = (w >> 16) | (w << 48);
    uint64_t r3 = (w >> 24) | (w << 40);
    uint64_t r4 = (w >> 32) | (w << 32);
    return !(haszero8(w ^ r1) | haszero8(w ^ r2) | haszero8(w ^ r3) | haszero8(w ^ r4));
}
__device__ __forceinline__ uint32_t pack4(int4 v) {
    return (uint32_t)(v.x & 255) | ((uint32_t)(v.y & 255) << 8) |
           ((uint32_t)(v.z & 255) << 16) | ((uint32_t)(v.w & 255) << 24);
}
__device__ __forceinline__ uint32_t bsel16(uint4 f, uint32_t b) {
    uint32_t w01 = (b & 4u) ? f.y : f.x;
    uint32_t w23 = (b & 4u) ? f.w : f.z;
    uint32_t w   = (b & 8u) ? w23 : w01;
    return (w >> ((b & 3u) << 3)) & 255u;
}
// r.byte[i] = g.byte[f.byte[i]]  (byte values in [0,16)) -- proven rounds 5-7
__device__ __forceinline__ uint4 comp16(uint4 g, uint4 f) {
    uint4 r;
#if __has_builtin(__builtin_amdgcn_perm)
    #define C16W(fw, out) do { \
        uint32_t sel = (fw) & 0x07070707u; \
        uint32_t lo = __builtin_amdgcn_perm(g.y, g.x, sel); \
        uint32_t hi = __builtin_amdgcn_perm(g.w, g.z, sel); \
        uint32_t m = ((fw) & 0x08080808u) >> 3; m = (m << 8) - m; \
        out = (lo & ~m) | (hi & m); } while (0)
    C16W(f.x, r.x); C16W(f.y, r.y); C16W(f.z, r.z); C16W(f.w, r.w);
    #undef C16W
#else
    #define C16B(fw, out) do { uint32_t o = 0; \
        o |= bsel16(g, (fw) & 15u); \
        o |= bsel16(g, ((fw) >> 8) & 15u) << 8; \
        o |= bsel16(g, ((fw) >> 16) & 15u) << 16; \
        o |= bsel16(g, ((fw) >> 24) & 15u) << 24; \
        out = o; } while (0)
    C16B(f.x, r.x); C16B(f.y, r.y); C16B(f.z, r.z); C16B(f.w, r.w);
    #undef C16B
#endif
    return r;
}

__global__ __launch_bounds__(NT) void ep_fused(const int* __restrict__ tokens,
                                               int* __restrict__ out) {
    __shared__ uint32_t tok32[2056];     // 8192 tokens u8-packed + 32B zero pad
    __shared__ uint16_t stop16[512];
    __shared__ uint32_t stopb[258];
    __shared__ uint8_t  sizes8[SEQ];
    __shared__ uint32_t exitf32[NCH * 4];
    __shared__ uint32_t cntf32[NCH * 4];
    __shared__ uint8_t  entry_s[NCH];
    __shared__ uint16_t pbase_s[NCH];
    __shared__ uint16_t starts_s[4100];
    __shared__ int wsum_s[8];
    __shared__ int S_s[4];

    const int bx = blockIdx.x;
    const int b = bx >> 3, qc = bx & 7;          // sequence, emission eighth
    const int tid = threadIdx.x;
    const int lane = tid & 63, wid = tid >> 6;

    // ---- A: coalesced load, pack tokens to u8 (proven) ----
    {
        const int4* t4 = (const int4*)(tokens + (size_t)b * SEQ);
        #pragma unroll
        for (int k = 0; k < 4; ++k) { int g = k * NT + tid; tok32[g] = pack4(t4[g]); }
        if (tid < 8) tok32[2048 + tid] = 0u;
    }
    __syncthreads();

    // ---- B: stop bits (exact integer test; proven) ----
    {
        const int base = tid * 4;
        uint64_t win = (uint64_t)tok32[base] | ((uint64_t)tok32[base + 1] << 32);
        uint32_t bits = 0;
        #pragma unroll
        for (int k = 0; k < 4; ++k) {
            uint32_t nx = tok32[base + 2 + k];
            #pragma unroll
            for (int m = 0; m < 4; ++m) {
                int j = tid * 16 + k * 4 + m;
                if (j <= SEQ - 8 && distinct8(win)) bits |= (1u << (k * 4 + m));
                win = (win >> 8) | ((uint64_t)(nx & 255u) << 56);
                nx >>= 8;
            }
        }
        stop16[tid] = (uint16_t)bits;
    }
    __syncthreads();
    if (tid < 256) stopb[tid] = (uint32_t)stop16[2 * tid] | ((uint32_t)stop16[2 * tid + 1] << 16);
    if (tid < 2) stopb[256 + tid] = 0u;
    __syncthreads();

    // ---- Bs: sizes (proven formula) ----
    {
        #pragma unroll 4
        for (int m = 0; m < 16; ++m) {
            int i = tid * 16 + m;
            int bp = i + 2, w = bp >> 5;
            uint64_t comb = (uint64_t)stopb[w] | ((uint64_t)stopb[w + 1] << 32);
            uint32_t win14 = (uint32_t)(comb >> (bp & 31)) & 0x3FFFu;
            int sz = win14 ? (2 + __builtin_ctz(win14)) : min(16, SEQ - i);
            sizes8[i] = (uint8_t)sz;
        }
    }
    __syncthreads();

    // ---- T: chunk transfer functions (proven) ----
    {
        const int ch = tid >> 1, e0 = (tid & 1) << 3;
        const int cb = ch * 32, lim = cb + 32;
        int pp[8], cc[8];
        #pragma unroll
        for (int k = 0; k < 8; ++k) { pp[k] = cb + e0 + k; cc[k] = 0; }
        for (int it = 0; it < 17; ++it) {
            bool any = false;
            #pragma unroll
            for (int k = 0; k < 8; ++k) {
                bool a = pp[k] < lim;
                int s = (int)sizes8[a ? pp[k] : cb];
                if (a) { cc[k] += 1; pp[k] += s; any = true; }
            }
            if (!any) break;
        }
        uint32_t xw0 = 0, xw1 = 0, cw0 = 0, cw1 = 0;
        #pragma unroll
        for (int k = 0; k < 4; ++k) {
            xw0 |= (uint32_t)(pp[k] - lim) << (k * 8);
            cw0 |= (uint32_t)cc[k] << (k * 8);
            xw1 |= (uint32_t)(pp[k + 4] - lim) << (k * 8);
            cw1 |= (uint32_t)cc[k + 4] << (k * 8);
        }
        int wb = (ch << 2) + ((tid & 1) << 1);
        exitf32[wb] = xw0; exitf32[wb + 1] = xw1;
        cntf32[wb]  = cw0; cntf32[wb + 1]  = cw1;
    }
    __syncthreads();

    // ---- S: wave-0 function scan -> chunk entries (proven) ----
    if (tid < 64) {
        const uint4* xf4 = (const uint4*)exitf32;
        uint4 f0 = xf4[tid * 4], f1 = xf4[tid * 4 + 1],
              f2 = xf4[tid * 4 + 2], f3 = xf4[tid * 4 + 3];
        uint4 g = comp16(f1, f0);
        g = comp16(f2, g);
        g = comp16(f3, g);
        #pragma unroll
        for (int d = 1; d < 64; d <<= 1) {
            uint4 o;
            o.x = (uint32_t)__shfl_up((int)g.x, d);
            o.y = (uint32_t)__shfl_up((int)g.y, d);
            o.z = (uint32_t)__shfl_up((int)g.z, d);
            o.w = (uint32_t)__shfl_up((int)g.w, d);
            if (tid >= d) g = comp16(g, o);
        }
        uint4 E;
        E.x = (uint32_t)__shfl_up((int)g.x, 1);
        E.y = (uint32_t)__shfl_up((int)g.y, 1);
        E.z = (uint32_t)__shfl_up((int)g.z, 1);
        E.w = (uint32_t)__shfl_up((int)g.w, 1);
        if (tid == 0) E = make_uint4(0x03020100u, 0x07060504u, 0x0B0A0908u, 0x0F0E0D0Cu);
        uint32_t e0 = E.x & 255u;
        uint32_t e1 = bsel16(f0, e0);
        uint32_t e2 = bsel16(f1, e1);
        uint32_t e3 = bsel16(f2, e2);
        entry_s[tid * 4 + 0] = (uint8_t)e0;
        entry_s[tid * 4 + 1] = (uint8_t)e1;
        entry_s[tid * 4 + 2] = (uint8_t)e2;
        entry_s[tid * 4 + 3] = (uint8_t)e3;
    }
    __syncthreads();

    // ---- C2: per-chunk count + prefix sum -> patch bases (proven) ----
    {
        int cnt = 0;
        if (tid < NCH) cnt = (int)((const uint8_t*)cntf32)[tid * 16 + (int)entry_s[tid]];
        int inc = cnt;
        #pragma unroll
        for (int d = 1; d < 64; d <<= 1) { int o = __shfl_up(inc, d); if (lane >= d) inc += o; }
        if (lane == 63) wsum_s[wid] = inc;
        __syncthreads();
        int off = 0;
        for (int w = 0; w < wid; ++w) off += wsum_s[w];
        if (tid < NCH) pbase_s[tid] = (uint16_t)(off + inc - cnt);
        if (tid == NCH - 1) S_s[0] = off + inc;   // total P
    }
    __syncthreads();

    // ---- X: per-chunk expansion + sentinel fill (disjoint ranges, one phase) ----
    if (tid < NCH) {
        int pb = (int)pbase_s[tid];
        int p = tid * 32 + (int)entry_s[tid];
        const int lim = tid * 32 + 32;
        while (p < lim) {
            starts_s[pb++] = (uint16_t)p;
            p += (int)sizes8[p];
        }
    }
    {
        const int P = S_s[0];                    // valid: barrier after C2
        for (int i = P + tid; i < 4098; i += NT) starts_s[i] = (uint16_t)SEQ;
    }
    __syncthreads();

    // ---- G: coalesced emission, 4-lane groups, alignbit extraction ----
    {
        int* outp = out + (size_t)b * (MAXP * 16);
        int* outm = out + (size_t)NB * MAXP * 16 + (size_t)b * MAXP;
        const int j = tid & 3;
        #pragma unroll
        for (int it = 0; it < (MAXP / RED) / (NT / 4); ++it) {   // 4 passes
            const int p = qc * (MAXP / RED) + it * (NT / 4) + (tid >> 2);
            const int st = (int)starts_s[p];
            const int sz = (int)starts_s[p + 1] - st;            // 0..16
            const int base = (st >> 2) + j;
            const uint32_t sh = (uint32_t)(st & 3) * 8u;
            uint32_t lo = tok32[base], hi = tok32[base + 1];
            uint32_t pk = (uint32_t)((((uint64_t)hi << 32) | lo) >> sh);
            int rem = sz - 4 * j;
            rem = (rem < 0) ? 0 : (rem > 4 ? 4 : rem);
            pk &= (uint32_t)((1ULL << (8 * rem)) - 1ULL);
            ((int4*)outp)[(size_t)p * 4 + j] =
                make_int4((int)(pk & 255u), (int)((pk >> 8) & 255u),
                          (int)((pk >> 16) & 255u), (int)(pk >> 24));
        }
        {
            const int p = qc * (MAXP / RED) + tid;               // 512 masks, 1 pass
            outm[p] = ((int)starts_s[p] < SEQ) ? 1 : 0;
        }
    }
}

extern "C" void kernel_launch(void* const* d_in, const int* in_sizes, int n_in,
                              void* d_out, int out_size, void* d_ws, size_t ws_size,
                              hipStream_t stream) {
    const int* tokens = (const int*)d_in[0];
    int* out = (int*)d_out;
    ep_fused<<<dim3(NB * RED), dim3(NT), 0, stream>>>(tokens, out);
}

// Round 9
// 29.853 us; speedup vs baseline: 1.2727x; 1.2727x over previous
//
#include <hip/hip_runtime.h>
#include <stdint.h>

#define SEQ   8192
#define NB    128
#define MAXP  4096
#define TOT4  (NB * SEQ / 4)

// ---- ws layout (u32 units) ----
#define WS_SIZES  0               // 128 * 2048 u32 (byte per position)
#define WS_EXITF  262144          // 128 * 1024 u32 (256 chunks * 16B exit fn)
#define WS_CNTF   393216          // 128 * 1024 u32
#define WS_TOTAL  524288
#define WS_NEEDED ((size_t)WS_TOTAL * 4)

__device__ __forceinline__ bool haszero8(uint64_t v) {
    return ((v - 0x0101010101010101ULL) & ~v & 0x8080808080808080ULL) != 0ULL;
}
__device__ __forceinline__ bool distinct8(uint64_t w) {
    uint64_t r1 = (w >> 8)  | (w << 56);
    uint64_t r2 = (w >> 16) | (w << 48);
    uint64_t r3 = (w >> 24) | (w << 40);
    uint64_t r4 = (w >> 32) | (w << 32);
    return !(haszero8(w ^ r1) | haszero8(w ^ r2) | haszero8(w ^ r3) | haszero8(w ^ r4));
}
__device__ __forceinline__ uint32_t pack4(int4 v) {
    return (uint32_t)(v.x & 255) | ((uint32_t)(v.y & 255) << 8) |
           ((uint32_t)(v.z & 255) << 16) | ((uint32_t)(v.w & 255) << 24);
}
__device__ __forceinline__ uint32_t bsel16(uint4 f, uint32_t b) {
    uint32_t w01 = (b & 4u) ? f.y : f.x;
    uint32_t w23 = (b & 4u) ? f.w : f.z;
    uint32_t w   = (b & 8u) ? w23 : w01;
    return (w >> ((b & 3u) << 3)) & 255u;
}
// r.byte[i] = g.byte[f.byte[i]]  (byte values in [0,16)) -- proven rounds 5-8
__device__ __forceinline__ uint4 comp16(uint4 g, uint4 f) {
    uint4 r;
#if __has_builtin(__builtin_amdgcn_perm)
    #define C16W(fw, out) do { \
        uint32_t sel = (fw) & 0x07070707u; \
        uint32_t lo = __builtin_amdgcn_perm(g.y, g.x, sel); \
        uint32_t hi = __builtin_amdgcn_perm(g.w, g.z, sel); \
        uint32_t m = ((fw) & 0x08080808u) >> 3; m = (m << 8) - m; \
        out = (lo & ~m) | (hi & m); } while (0)
    C16W(f.x, r.x); C16W(f.y, r.y); C16W(f.z, r.z); C16W(f.w, r.w);
    #undef C16W
#else
    #define C16B(fw, out) do { uint32_t o = 0; \
        o |= bsel16(g, (fw) & 15u); \
        o |= bsel16(g, ((fw) >> 8) & 15u) << 8; \
        o |= bsel16(g, ((fw) >> 16) & 15u) << 16; \
        o |= bsel16(g, ((fw) >> 24) & 15u) << 24; \
        out = o; } while (0)
    C16B(f.x, r.x); C16B(f.y, r.y); C16B(f.z, r.z); C16B(f.w, r.w);
    #undef C16B
#endif
    return r;
}

// ---------- K1: quarter-sequence prep (R6 verbatim, proven) -----------------------
__global__ __launch_bounds__(256) void ep_prep(const int* __restrict__ tokens,
                                               uint32_t* __restrict__ ws) {
    __shared__ uint32_t tok32[520];
    __shared__ uint8_t  stop8[264];
    __shared__ uint32_t stopb[66];
    __shared__ uint8_t  sizes8s[2048];

    const int bq = blockIdx.x;
    const int b = bq >> 2, q = bq & 3;
    const int tid = threadIdx.x;
    const int4* t4 = (const int4*)tokens;
    const int gbase = b * 2048 + q * 512;

    tok32[tid]       = pack4(t4[gbase + tid]);
    tok32[256 + tid] = pack4(t4[gbase + 256 + tid]);
    if (tid < 8) {
        int g4 = gbase + 512 + tid;
        tok32[512 + tid] = (g4 < TOT4) ? pack4(t4[g4]) : 0u;
    }
    if (tid >= 2 && tid < 8) stop8[256 + tid] = 0;
    if (tid == 0) stopb[65] = 0;
    __syncthreads();

    for (int g = tid; g < 258; g += 256) {
        const int wb = g * 2;
        uint64_t win = (uint64_t)tok32[wb] | ((uint64_t)tok32[wb + 1] << 32);
        uint32_t byte = 0;
        #pragma unroll
        for (int k = 0; k < 2; ++k) {
            uint32_t nx = tok32[wb + 2 + k];
            #pragma unroll
            for (int m = 0; m < 4; ++m) {
                int jg = q * 2048 + g * 8 + k * 4 + m;
                if (jg <= SEQ - 8 && distinct8(win)) byte |= 1u << (k * 4 + m);
                win = (win >> 8) | ((uint64_t)(nx & 255u) << 56);
                nx >>= 8;
            }
        }
        stop8[g] = (uint8_t)byte;
    }
    __syncthreads();
    if (tid < 65)
        stopb[tid] = (uint32_t)stop8[4 * tid] | ((uint32_t)stop8[4 * tid + 1] << 8)
                   | ((uint32_t)stop8[4 * tid + 2] << 16) | ((uint32_t)stop8[4 * tid + 3] << 24);
    __syncthreads();

    {
        #pragma unroll
        for (int w = 0; w < 2; ++w) {
            uint32_t acc = 0;
            #pragma unroll
            for (int m = 0; m < 4; ++m) {
                int il = tid * 8 + w * 4 + m;
                int bp = il + 2, ww = bp >> 5;
                uint64_t comb = (uint64_t)stopb[ww] | ((uint64_t)stopb[ww + 1] << 32);
                uint32_t win14 = (uint32_t)(comb >> (bp & 31)) & 0x3FFFu;
                int ig = q * 2048 + il;
                int sz = win14 ? (2 + __builtin_ctz(win14)) : min(16, SEQ - ig);
                acc |= (uint32_t)sz << (m * 8);
            }
            ((uint32_t*)sizes8s)[tid * 2 + w] = acc;
            ws[WS_SIZES + b * 2048 + q * 512 + tid * 2 + w] = acc;
        }
    }
    __syncthreads();

    {
        const int ch = tid >> 2, sub = tid & 3;
        const int cb = ch * 32;
        int pp[4], cc[4];
        #pragma unroll
        for (int k = 0; k < 4; ++k) { pp[k] = cb + sub * 4 + k; cc[k] = 0; }
        for (int it = 0; it < 17; ++it) {
            #pragma unroll
            for (int k = 0; k < 4; ++k) {
                bool a = pp[k] < cb + 32;
                int s = (int)sizes8s[a ? pp[k] : cb];
                if (a) { cc[k]++; pp[k] += s; }
            }
        }
        uint32_t xw = 0, cw = 0;
        #pragma unroll
        for (int k = 0; k < 4; ++k) {
            xw |= (uint32_t)(pp[k] - (cb + 32)) << (k * 8);
            cw |= (uint32_t)cc[k] << (k * 8);
        }
        const int fidx = b * 1024 + (q * 64 + ch) * 4 + sub;
        ws[WS_EXITF + fidx] = xw;
        ws[WS_CNTF  + fidx] = cw;
    }
}

// ---------- K2: emission with in-block redundant scan (2048 blocks, 8/CU) ---------
__global__ __launch_bounds__(256) void ep_emit2(const int* __restrict__ tokens,
                                                const uint32_t* __restrict__ ws,
                                                int* __restrict__ out) {
    __shared__ uint32_t xf_l[1024];     // exit fns (4 KB)
    __shared__ uint32_t cf_l[1024];     // cnt fns (4 KB)
    __shared__ uint32_t tokw[140];      // 544 tokens u8-packed
    __shared__ uint8_t  sz_l[512];
    __shared__ uint8_t  ent_l[256];
    __shared__ uint16_t pb_l[256];
    __shared__ uint16_t lstarts[264];
    __shared__ int wsum_s[4];
    __shared__ int S2_s[4];             // 0:P  1:nloc

    const int bx = blockIdx.x;
    const int b = bx >> 4, c = bx & 15, tid = threadIdx.x;
    const int lane = tid & 63, wid = tid >> 6;

    // ---- stage ----
    {
        const int fb = b * 1024;
        #pragma unroll
        for (int k = 0; k < 4; ++k) {
            xf_l[k * 256 + tid] = ws[WS_EXITF + fb + k * 256 + tid];
            cf_l[k * 256 + tid] = ws[WS_CNTF  + fb + k * 256 + tid];
        }
        if (tid < 136) {
            int g4 = b * 2048 + c * 128 + tid;
            tokw[tid] = (g4 < TOT4) ? pack4(((const int4*)tokens)[g4]) : 0u;
        }
        if (tid < 128) ((uint32_t*)sz_l)[tid] = ws[WS_SIZES + b * 2048 + c * 128 + tid];
    }
    __syncthreads();

    // ---- wave-0 scan of exit fns -> entries of all 256 chunks (proven) ----
    if (tid < 64) {
        const uint4* xf4 = (const uint4*)xf_l;
        uint4 f0 = xf4[tid * 4], f1 = xf4[tid * 4 + 1],
              f2 = xf4[tid * 4 + 2], f3 = xf4[tid * 4 + 3];
        uint4 g = comp16(f1, f0);
        g = comp16(f2, g);
        g = comp16(f3, g);
        #pragma unroll
        for (int d = 1; d < 64; d <<= 1) {
            uint4 o;
            o.x = (uint32_t)__shfl_up((int)g.x, d);
            o.y = (uint32_t)__shfl_up((int)g.y, d);
            o.z = (uint32_t)__shfl_up((int)g.z, d);
            o.w = (uint32_t)__shfl_up((int)g.w, d);
            if (tid >= d) g = comp16(g, o);
        }
        uint4 E;
        E.x = (uint32_t)__shfl_up((int)g.x, 1);
        E.y = (uint32_t)__shfl_up((int)g.y, 1);
        E.z = (uint32_t)__shfl_up((int)g.z, 1);
        E.w = (uint32_t)__shfl_up((int)g.w, 1);
        if (tid == 0) E = make_uint4(0x03020100u, 0x07060504u, 0x0B0A0908u, 0x0F0E0D0Cu);
        uint32_t e0 = E.x & 255u;
        uint32_t e1 = bsel16(f0, e0);
        uint32_t e2 = bsel16(f1, e1);
        uint32_t e3 = bsel16(f2, e2);
        ent_l[tid * 4 + 0] = (uint8_t)e0;
        ent_l[tid * 4 + 1] = (uint8_t)e1;
        ent_l[tid * 4 + 2] = (uint8_t)e2;
        ent_l[tid * 4 + 3] = (uint8_t)e3;
    }
    __syncthreads();

    // ---- counts at entries + 256-wide prefix -> pb_l, P ----
    {
        int cnt = (int)((const uint8_t*)cf_l)[tid * 16 + (int)ent_l[tid]];
        int inc = cnt;
        #pragma unroll
        for (int d = 1; d < 64; d <<= 1) { int o = __shfl_up(inc, d); if (lane >= d) inc += o; }
        if (lane == 63) wsum_s[wid] = inc;
        __syncthreads();
        int off = 0;
        for (int w = 0; w < wid; ++w) off += wsum_s[w];
        pb_l[tid] = (uint16_t)(off + inc - cnt);
        if (tid == 255) S2_s[0] = off + inc;     // total P
    }
    __syncthreads();

    // ---- expand this block's 16 chunks (local coords) ----
    if (tid < 16) {
        const int ch = c * 16 + tid;
        int p = tid * 32 + (int)ent_l[ch];
        const int lim = tid * 32 + 32;
        int pbl = (int)pb_l[ch] - (int)pb_l[c * 16];
        while (p < lim) { lstarts[pbl++] = (uint16_t)p; p += (int)sz_l[p]; }
    }
    if (tid == 16) {
        const int P = S2_s[0];
        int nloc = ((c < 15) ? (int)pb_l[c * 16 + 16] : P) - (int)pb_l[c * 16];
        S2_s[1] = nloc;
        lstarts[nloc] = (uint16_t)(512 + ((c < 15) ? (int)ent_l[c * 16 + 16] : 0));
    }
    __syncthreads();

    // ---- emit: 4-lane groups, alignbit extraction, coalesced (proven R8) ----
    const int nloc = S2_s[1], pb0 = (int)pb_l[c * 16], P = S2_s[0];
    int* outp = out + (size_t)b * (MAXP * 16);
    int* outm = out + (size_t)NB * MAXP * 16 + (size_t)b * MAXP;
    const int j = tid & 3;
    #pragma unroll
    for (int it = 0; it < 4; ++it) {
        const int pl = it * 64 + (tid >> 2);
        if (pl < nloc) {
            const int st = (int)lstarts[pl];
            const int szp = (int)lstarts[pl + 1] - st;
            const int base = (st >> 2) + j;
            const uint32_t sh = (uint32_t)(st & 3) * 8u;
            uint32_t lo = tokw[base], hi = tokw[base + 1];
            uint32_t pk = (uint32_t)((((uint64_t)hi << 32) | lo) >> sh);
            int rem = szp - 4 * j;
            rem = (rem < 0) ? 0 : (rem > 4 ? 4 : rem);
            pk &= (uint32_t)((1ULL << (8 * rem)) - 1ULL);
            ((int4*)outp)[(size_t)(pb0 + pl) * 4 + j] =
                make_int4((int)(pk & 255u), (int)((pk >> 8) & 255u),
                          (int)((pk >> 16) & 255u), (int)(pk >> 24));
        }
    }
    for (int pm = tid; pm < nloc; pm += 256) outm[pb0 + pm] = 1;
    {
        const int idx = c * 256 + tid;           // static tile, covers [0,4096)
        if (idx >= P) {
            int4 z = make_int4(0, 0, 0, 0);
            int4* d = (int4*)(outp + (size_t)idx * 16);
            d[0] = z; d[1] = z; d[2] = z; d[3] = z;
            outm[idx] = 0;
        }
    }
}

// ---------- Fallback (ws too small): proven round-1 monolithic ---------------------
__global__ __launch_bounds__(256) void ep_mono(const int* __restrict__ tokens,
                                               int* __restrict__ out) {
    __shared__ uint32_t tok32[2052];
    __shared__ uint32_t stopb[258];
    __shared__ uint8_t  sizes_s[SEQ];
    __shared__ uint16_t f_s[SEQ];
    __shared__ uint16_t starts_s[MAXP + 4];
    __shared__ int      entry_s[130];
    __shared__ int      base_s[130];
    __shared__ int      P_s, nv_s;

    const int b = blockIdx.x, tid = threadIdx.x;
    const int* tseq = tokens + (size_t)b * SEQ;
    {
        const int4* t4 = (const int4*)tseq;
        #pragma unroll
        for (int k = 0; k < 8; ++k) { int g = k * 256 + tid; tok32[g] = pack4(t4[g]); }
        if (tid < 4) tok32[2048 + tid] = 0u;
        if (tid < 2) stopb[256 + tid] = 0u;
    }
    __syncthreads();
    {
        const int base = tid * 8;
        uint64_t win = (uint64_t)tok32[base] | ((uint64_t)tok32[base + 1] << 32);
        uint32_t bits = 0;
        #pragma unroll
        for (int k = 0; k < 8; ++k) {
            uint32_t nx = tok32[base + 2 + k];
            #pragma unroll
            for (int m = 0; m < 4; ++m) {
                int j = tid * 32 + k * 4 + m;
                if (j <= SEQ - 8 && distinct8(win)) bits |= (1u << (k * 4 + m));
                win = (win >> 8) | ((uint64_t)(nx & 255u) << 56);
                nx >>= 8;
            }
        }
        stopb[tid] = bits;
    }
    __syncthreads();
    {
        const int i0 = tid * 32;
        #pragma unroll 4
        for (int m = 0; m < 32; ++m) {
            int i = i0 + m, bp = i + 2, w = bp >> 5;
            uint64_t comb = (uint64_t)stopb[w] | ((uint64_t)stopb[w + 1] << 32);
            uint32_t win14 = (uint32_t)(comb >> (bp & 31)) & 0x3FFFu;
            int sz = win14 ? (2 + __builtin_ctz(win14)) : min(16, SEQ - i);
            sizes_s[i] = (uint8_t)sz;
        }
    }
    __syncthreads();
    if (tid < 128) {
        const int cbase = tid * 64, cend = cbase + 64;
        for (int i = cend - 1; i >= cbase; --i) {
            int j = i + (int)sizes_s[i];
            uint16_t fv;
            if (j >= cend) fv = (uint16_t)((j - cbase) | (1u << 8));
            else { uint16_t fj = f_s[j];
                   fv = (uint16_t)((fj & 255u) | ((uint32_t)((fj >> 8) + 1u) << 8)); }
            f_s[i] = fv;
        }
    }
    __syncthreads();
    if (tid == 0) {
        int i = 0, pidx = 0, m = 0;
        while (i < SEQ) {
            entry_s[m] = i; base_s[m] = pidx;
            uint16_t fv = f_s[i];
            pidx += (int)(fv >> 8);
            i = (i & ~63) + (int)(fv & 255u);
            ++m;
        }
        P_s = pidx; nv_s = m;
        starts_s[pidx] = (uint16_t)SEQ;
    }
    __syncthreads();
    if (tid < nv_s) {
        int i = entry_s[tid], p = base_s[tid];
        const int cend = (i & ~63) + 64;
        while (i < cend) { starts_s[p++] = (uint16_t)i; i += (int)sizes_s[i]; }
    }
    __syncthreads();
    const int P = P_s;
    int* outp = out + (size_t)b * MAXP * 16;
    int* outm = out + (size_t)NB * MAXP * 16 + (size_t)b * MAXP;
    const uint8_t* tok8 = (const uint8_t*)tok32;
    for (int p = tid; p < MAXP; p += 256) {
        int4 o0 = make_int4(0,0,0,0), o1 = o0, o2 = o0, o3 = o0;
        int msk = 0;
        if (p < P) {
            msk = 1;
            int st = (int)starts_s[p];
            int sz = (int)starts_s[p + 1] - st;
            int t[16];
            #pragma unroll
            for (int l = 0; l < 16; ++l) t[l] = (l < sz) ? (int)tok8[st + l] : 0;
            o0 = make_int4(t[0],t[1],t[2],t[3]);   o1 = make_int4(t[4],t[5],t[6],t[7]);
            o2 = make_int4(t[8],t[9],t[10],t[11]); o3 = make_int4(t[12],t[13],t[14],t[15]);
        }
        int4* dst = (int4*)(outp + (size_t)p * 16);
        dst[0] = o0; dst[1] = o1; dst[2] = o2; dst[3] = o3;
        outm[p] = msk;
    }
}

extern "C" void kernel_launch(void* const* d_in, const int* in_sizes, int n_in,
                              void* d_out, int out_size, void* d_ws, size_t ws_size,
                              hipStream_t stream) {
    const int* tokens = (const int*)d_in[0];
    int* out = (int*)d_out;
    if (ws_size >= WS_NEEDED) {
        uint32_t* ws = (uint32_t*)d_ws;
        ep_prep<<<dim3(NB * 4), dim3(256), 0, stream>>>(tokens, ws);
        ep_emit2<<<dim3(NB * 16), dim3(256), 0, stream>>>(tokens, ws, out);
    } else {
        ep_mono<<<dim3(NB), dim3(256), 0, stream>>>(tokens, out);
    }
}

// Round 10
// 27.974 us; speedup vs baseline: 1.3582x; 1.0672x over previous
//
#include <hip/hip_runtime.h>
#include <stdint.h>

#define SEQ  8192
#define NB   128
#define MAXP 4096
#define NT   512
#define RED  2                     // blocks per sequence (grid = 256 = 1 block/CU)
#define NCH  256                   // 32-wide chunks per sequence

__device__ __forceinline__ bool haszero8(uint64_t v) {
    return ((v - 0x0101010101010101ULL) & ~v & 0x8080808080808080ULL) != 0ULL;
}
__device__ __forceinline__ bool distinct8(uint64_t w) {
    uint64_t r1 = (w >> 8)  | (w << 56);
    uint64_t r2 = (w >> 16) | (w << 48);
    uint64_t r3 = (w >> 24) | (w << 40);
    uint64_t r4 = (w >> 32) | (w << 32);
    return !(haszero8(w ^ r1) | haszero8(w ^ r2) | haszero8(w ^ r3) | haszero8(w ^ r4));
}
__device__ __forceinline__ uint32_t pack4(int4 v) {
    return (uint32_t)(v.x & 255) | ((uint32_t)(v.y & 255) << 8) |
           ((uint32_t)(v.z & 255) << 16) | ((uint32_t)(v.w & 255) << 24);
}
__device__ __forceinline__ uint32_t bsel16(uint4 f, uint32_t b) {
    uint32_t w01 = (b & 4u) ? f.y : f.x;
    uint32_t w23 = (b & 4u) ? f.w : f.z;
    uint32_t w   = (b & 8u) ? w23 : w01;
    return (w >> ((b & 3u) << 3)) & 255u;
}
// r.byte[i] = g.byte[f.byte[i]]  (byte values in [0,16)) -- proven rounds 5-9
__device__ __forceinline__ uint4 comp16(uint4 g, uint4 f) {
    uint4 r;
#if __has_builtin(__builtin_amdgcn_perm)
    #define C16W(fw, out) do { \
        uint32_t sel = (fw) & 0x07070707u; \
        uint32_t lo = __builtin_amdgcn_perm(g.y, g.x, sel); \
        uint32_t hi = __builtin_amdgcn_perm(g.w, g.z, sel); \
        uint32_t m = ((fw) & 0x08080808u) >> 3; m = (m << 8) - m; \
        out = (lo & ~m) | (hi & m); } while (0)
    C16W(f.x, r.x); C16W(f.y, r.y); C16W(f.z, r.z); C16W(f.w, r.w);
    #undef C16W
#else
    #define C16B(fw, out) do { uint32_t o = 0; \
        o |= bsel16(g, (fw) & 15u); \
        o |= bsel16(g, ((fw) >> 8) & 15u) << 8; \
        o |= bsel16(g, ((fw) >> 16) & 15u) << 16; \
        o |= bsel16(g, ((fw) >> 24) & 15u) << 24; \
        out = o; } while (0)
    C16B(f.x, r.x); C16B(f.y, r.y); C16B(f.z, r.z); C16B(f.w, r.w);
    #undef C16B
#endif
    return r;
}
// proven size rule, reading the stop bitmap directly
__device__ __forceinline__ int psize(const uint32_t* stopb, int p) {
    int bp = p + 2, w = bp >> 5;
    uint64_t comb = (uint64_t)stopb[w] | ((uint64_t)stopb[w + 1] << 32);
    uint32_t win14 = (uint32_t)(comb >> (bp & 31)) & 0x3FFFu;
    return win14 ? (2 + __builtin_ctz(win14)) : min(16, SEQ - p);
}

__global__ __launch_bounds__(NT) void ep_fused(const int* __restrict__ tokens,
                                               int* __restrict__ out) {
    __shared__ uint32_t tok32[2056];     // 8192 tokens u8-packed + 32B zero pad
    __shared__ uint32_t stopb[258];
    __shared__ uint32_t exitf32[NCH * 4];
    __shared__ uint32_t cntf32[NCH * 4];
    __shared__ uint8_t  entry_s[NCH];
    __shared__ uint16_t pbase_s[NCH];
    __shared__ uint16_t starts_s[4100];
    __shared__ int S_s[2];               // 0: total P

    const int bx = blockIdx.x;
    const int b = bx >> 1, qc = bx & 1;  // sequence, emission half
    const int tid = threadIdx.x;

    // ---- A: coalesced load, pack tokens to u8 (proven) ----
    {
        const int4* t4 = (const int4*)(tokens + (size_t)b * SEQ);
        #pragma unroll
        for (int k = 0; k < 4; ++k) { int g = k * NT + tid; tok32[g] = pack4(t4[g]); }
        if (tid < 8) tok32[2048 + tid] = 0u;
        if (tid < 2) stopb[256 + tid] = 0u;
    }
    __syncthreads();                     // b1

    // ---- B: stop bits (proven) + intra-wave pack to stopb (no extra barrier) ----
    {
        const int base = tid * 4;
        uint64_t win = (uint64_t)tok32[base] | ((uint64_t)tok32[base + 1] << 32);
        uint32_t bits = 0;
        #pragma unroll
        for (int k = 0; k < 4; ++k) {
            uint32_t nx = tok32[base + 2 + k];
            #pragma unroll
            for (int m = 0; m < 4; ++m) {
                int j = tid * 16 + k * 4 + m;
                if (j <= SEQ - 8 && distinct8(win)) bits |= (1u << (k * 4 + m));
                win = (win >> 8) | ((uint64_t)(nx & 255u) << 56);
                nx >>= 8;
            }
        }
        uint32_t other = (uint32_t)__shfl_xor((int)bits, 1);
        if ((tid & 1) == 0) stopb[tid >> 1] = (bits & 0xFFFFu) | (other << 16);
    }
    __syncthreads();                     // b2

    // ---- T: chunk transfer fns, walks straight off the bitmap (sizes8 deleted) ----
    {
        const int ch = tid >> 1, e0 = (tid & 1) << 3;
        const int cb = ch * 32, lim = cb + 32;
        int pp[8], cc[8];
        #pragma unroll
        for (int k = 0; k < 8; ++k) { pp[k] = cb + e0 + k; cc[k] = 0; }
        for (int it = 0; it < 17; ++it) {
            bool any = false;
            #pragma unroll
            for (int k = 0; k < 8; ++k) {
                bool a = pp[k] < lim;
                int s = psize(stopb, a ? pp[k] : cb);
                if (a) { cc[k] += 1; pp[k] += s; any = true; }
            }
            if (!any) break;
        }
        uint32_t xw0 = 0, xw1 = 0, cw0 = 0, cw1 = 0;
        #pragma unroll
        for (int k = 0; k < 4; ++k) {
            xw0 |= (uint32_t)(pp[k] - lim) << (k * 8);
            cw0 |= (uint32_t)cc[k] << (k * 8);
            xw1 |= (uint32_t)(pp[k + 4] - lim) << (k * 8);
            cw1 |= (uint32_t)cc[k + 4] << (k * 8);
        }
        int wb = (ch << 2) + ((tid & 1) << 1);
        exitf32[wb] = xw0; exitf32[wb + 1] = xw1;
        cntf32[wb]  = cw0; cntf32[wb + 1]  = cw1;
    }
    __syncthreads();                     // b3

    // ---- S: wave-0 mega-phase: fn scan -> entries, counts, pbase prefix, P ----
    if (tid < 64) {
        const uint4* xf4 = (const uint4*)exitf32;
        uint4 f0 = xf4[tid * 4], f1 = xf4[tid * 4 + 1],
              f2 = xf4[tid * 4 + 2], f3 = xf4[tid * 4 + 3];
        uint4 g = comp16(f1, f0);
        g = comp16(f2, g);
        g = comp16(f3, g);
        #pragma unroll
        for (int d = 1; d < 64; d <<= 1) {
            uint4 o;
            o.x = (uint32_t)__shfl_up((int)g.x, d);
            o.y = (uint32_t)__shfl_up((int)g.y, d);
            o.z = (uint32_t)__shfl_up((int)g.z, d);
            o.w = (uint32_t)__shfl_up((int)g.w, d);
            if (tid >= d) g = comp16(g, o);
        }
        uint4 E;
        E.x = (uint32_t)__shfl_up((int)g.x, 1);
        E.y = (uint32_t)__shfl_up((int)g.y, 1);
        E.z = (uint32_t)__shfl_up((int)g.z, 1);
        E.w = (uint32_t)__shfl_up((int)g.w, 1);
        if (tid == 0) E = make_uint4(0x03020100u, 0x07060504u, 0x0B0A0908u, 0x0F0E0D0Cu);
        uint32_t e0 = E.x & 255u;
        uint32_t e1 = bsel16(f0, e0);
        uint32_t e2 = bsel16(f1, e1);
        uint32_t e3 = bsel16(f2, e2);
        entry_s[tid * 4 + 0] = (uint8_t)e0;
        entry_s[tid * 4 + 1] = (uint8_t)e1;
        entry_s[tid * 4 + 2] = (uint8_t)e2;
        entry_s[tid * 4 + 3] = (uint8_t)e3;
        const uint8_t* cf = (const uint8_t*)cntf32;
        int c0 = (int)cf[(tid * 4 + 0) * 16 + (int)e0];
        int c1 = (int)cf[(tid * 4 + 1) * 16 + (int)e1];
        int c2 = (int)cf[(tid * 4 + 2) * 16 + (int)e2];
        int c3 = (int)cf[(tid * 4 + 3) * 16 + (int)e3];
        int s = c0 + c1 + c2 + c3;
        int incl = s;
        #pragma unroll
        for (int d = 1; d < 64; d <<= 1) { int o = __shfl_up(incl, d); if (tid >= d) incl += o; }
        int excl = incl - s;
        pbase_s[tid * 4 + 0] = (uint16_t)excl;
        pbase_s[tid * 4 + 1] = (uint16_t)(excl + c0);
        pbase_s[tid * 4 + 2] = (uint16_t)(excl + c0 + c1);
        pbase_s[tid * 4 + 3] = (uint16_t)(excl + c0 + c1 + c2);
        if (tid == 63) S_s[0] = incl;    // total P
    }
    __syncthreads();                     // b4

    // ---- X: expand chunks (bitmap walk) + sentinel fill, disjoint ranges ----
    if (tid < NCH) {
        int pb = (int)pbase_s[tid];
        int p = tid * 32 + (int)entry_s[tid];
        const int lim = tid * 32 + 32;
        while (p < lim) {
            starts_s[pb++] = (uint16_t)p;
            p += psize(stopb, p);
        }
    }
    {
        const int P = S_s[0];
        for (int i = P + tid; i < 4098; i += NT) starts_s[i] = (uint16_t)SEQ;
    }
    __syncthreads();                     // b5

    // ---- G: emit this half; 4-lane groups, alignbit extraction (proven R8) ----
    {
        int* outp = out + (size_t)b * (MAXP * 16);
        int* outm = out + (size_t)NB * MAXP * 16 + (size_t)b * MAXP;
        const int j = tid & 3;
        #pragma unroll
        for (int it = 0; it < (MAXP / RED) / (NT / 4); ++it) {   // 16 passes
            const int p = qc * (MAXP / RED) + it * (NT / 4) + (tid >> 2);
            const int st = (int)starts_s[p];
            const int sz = (int)starts_s[p + 1] - st;            // 0..16 (0 when p>=P)
            const int base = (st >> 2) + j;
            const uint32_t sh = (uint32_t)(st & 3) * 8u;
            uint32_t lo = tok32[base], hi = tok32[base + 1];
            uint32_t pk = (uint32_t)((((uint64_t)hi << 32) | lo) >> sh);
            int rem = sz - 4 * j;
            rem = (rem < 0) ? 0 : (rem > 4 ? 4 : rem);
            pk &= (uint32_t)((1ULL << (8 * rem)) - 1ULL);
            ((int4*)outp)[(size_t)p * 4 + j] =
                make_int4((int)(pk & 255u), (int)((pk >> 8) & 255u),
                          (int)((pk >> 16) & 255u), (int)(pk >> 24));
        }
        #pragma unroll
        for (int i = 0; i < (MAXP / RED) / NT; ++i) {            // 4 passes of masks
            const int p = qc * (MAXP / RED) + i * NT + tid;
            outm[p] = ((int)starts_s[p] < SEQ) ? 1 : 0;
        }
    }
}

extern "C" void kernel_launch(void* const* d_in, const int* in_sizes, int n_in,
                              void* d_out, int out_size, void* d_ws, size_t ws_size,
                              hipStream_t stream) {
    const int* tokens = (const int*)d_in[0];
    int* out = (int*)d_out;
    ep_fused<<<dim3(NB * RED), dim3(NT), 0, stream>>>(tokens, out);
}

// Round 11
// 21.474 us; speedup vs baseline: 1.7694x; 1.3027x over previous
//
#include <hip/hip_runtime.h>
#include <stdint.h>

#define SEQ  8192
#define NB   128
#define MAXP 4096
#define NT   512
#define RED  2                     // blocks per sequence (grid = 256 = 1 block/CU)
#define NCH  256                   // 32-wide chunks per sequence
#define STS  36                    // st_l stride in u16 (bank spread)

__device__ __forceinline__ bool haszero8(uint64_t v) {
    return ((v - 0x0101010101010101ULL) & ~v & 0x8080808080808080ULL) != 0ULL;
}
__device__ __forceinline__ bool distinct8(uint64_t w) {
    uint64_t r1 = (w >> 8)  | (w << 56);
    uint64_t r2 = (w >> 16) | (w << 48);
    uint64_t r3 = (w >> 24) | (w << 40);
    uint64_t r4 = (w >> 32) | (w << 32);
    return !(haszero8(w ^ r1) | haszero8(w ^ r2) | haszero8(w ^ r3) | haszero8(w ^ r4));
}
__device__ __forceinline__ uint32_t pack4(int4 v) {
    return (uint32_t)(v.x & 255) | ((uint32_t)(v.y & 255) << 8) |
           ((uint32_t)(v.z & 255) << 16) | ((uint32_t)(v.w & 255) << 24);
}
__device__ __forceinline__ uint32_t bsel16(uint4 f, uint32_t b) {
    uint32_t w01 = (b & 4u) ? f.y : f.x;
    uint32_t w23 = (b & 4u) ? f.w : f.z;
    uint32_t w   = (b & 8u) ? w23 : w01;
    return (w >> ((b & 3u) << 3)) & 255u;
}
// r.byte[i] = g.byte[f.byte[i]]  (byte values in [0,16)) -- proven rounds 5-10
__device__ __forceinline__ uint4 comp16(uint4 g, uint4 f) {
    uint4 r;
#if __has_builtin(__builtin_amdgcn_perm)
    #define C16W(fw, out) do { \
        uint32_t sel = (fw) & 0x07070707u; \
        uint32_t lo = __builtin_amdgcn_perm(g.y, g.x, sel); \
        uint32_t hi = __builtin_amdgcn_perm(g.w, g.z, sel); \
        uint32_t m = ((fw) & 0x08080808u) >> 3; m = (m << 8) - m; \
        out = (lo & ~m) | (hi & m); } while (0)
    C16W(f.x, r.x); C16W(f.y, r.y); C16W(f.z, r.z); C16W(f.w, r.w);
    #undef C16W
#else
    #define C16B(fw, out) do { uint32_t o = 0; \
        o |= bsel16(g, (fw) & 15u); \
        o |= bsel16(g, ((fw) >> 8) & 15u) << 8; \
        o |= bsel16(g, ((fw) >> 16) & 15u) << 16; \
        o |= bsel16(g, ((fw) >> 24) & 15u) << 24; \
        out = o; } while (0)
    C16B(f.x, r.x); C16B(f.y, r.y); C16B(f.z, r.z); C16B(f.w, r.w);
    #undef C16B
#endif
    return r;
}
// proven size rule, reading the stop bitmap directly
__device__ __forceinline__ int psize(const uint32_t* stopb, int p) {
    int bp = p + 2, w = bp >> 5;
    uint64_t comb = (uint64_t)stopb[w] | ((uint64_t)stopb[w + 1] << 32);
    uint32_t win14 = (uint32_t)(comb >> (bp & 31)) & 0x3FFFu;
    return win14 ? (2 + __builtin_ctz(win14)) : min(16, SEQ - p);
}

__global__ __launch_bounds__(NT) void ep_fused(const int* __restrict__ tokens,
                                               int* __restrict__ out) {
    __shared__ uint32_t tok32[2056];     // 8192 tokens u8-packed + 32B zero pad
    __shared__ uint32_t stopb[258];
    __shared__ uint16_t st_l[NCH * STS]; // per-position DP: exit | cnt<<8
    __shared__ uint32_t exitf32[NCH * 4];
    __shared__ uint8_t  entry_s[NCH];
    __shared__ uint16_t pbase_s[NCH];
    __shared__ uint16_t starts_s[4100];
    __shared__ int S_s[2];               // 0: total P

    const int bx = blockIdx.x;
    const int b = bx >> 1, qc = bx & 1;  // sequence, emission half
    const int tid = threadIdx.x;

    // ---- A: coalesced load, pack tokens to u8 (proven) ----
    {
        const int4* t4 = (const int4*)(tokens + (size_t)b * SEQ);
        #pragma unroll
        for (int k = 0; k < 4; ++k) { int g = k * NT + tid; tok32[g] = pack4(t4[g]); }
        if (tid < 8) tok32[2048 + tid] = 0u;
        if (tid < 2) stopb[256 + tid] = 0u;
    }
    __syncthreads();                     // b1

    // ---- B: stop bits (proven) + intra-wave pack to stopb ----
    {
        const int base = tid * 4;
        uint64_t win = (uint64_t)tok32[base] | ((uint64_t)tok32[base + 1] << 32);
        uint32_t bits = 0;
        #pragma unroll
        for (int k = 0; k < 4; ++k) {
            uint32_t nx = tok32[base + 2 + k];
            #pragma unroll
            for (int m = 0; m < 4; ++m) {
                int j = tid * 16 + k * 4 + m;
                if (j <= SEQ - 8 && distinct8(win)) bits |= (1u << (k * 4 + m));
                win = (win >> 8) | ((uint64_t)(nx & 255u) << 56);
                nx >>= 8;
            }
        }
        uint32_t other = (uint32_t)__shfl_xor((int)bits, 1);
        if ((tid & 1) == 0) stopb[tid >> 1] = (bits & 0xFFFFu) | (other << 16);
    }
    __syncthreads();                     // b2

    // ---- T: per-chunk backward DP (one thread per chunk; register stop window) ----
    if (tid < NCH) {
        const int c = tid;
        const uint64_t W = (uint64_t)stopb[c] | ((uint64_t)stopb[c + 1] << 32);
        uint16_t* st = st_l + c * STS;
        const int gb = c * 32;
        #pragma unroll 4
        for (int rel = 31; rel >= 0; --rel) {
            uint32_t win14 = (uint32_t)(W >> (rel + 2)) & 0x3FFFu;
            int sz = win14 ? (2 + __builtin_ctz(win14)) : min(16, SEQ - (gb + rel));
            int nxt = rel + sz;
            int ra = (nxt < 32) ? nxt : 0;           // clamped read (value unused if exit)
            uint32_t sv = st[ra];
            uint32_t cont = (sv & 0xFFu) | (((sv >> 8) + 1u) << 8);
            uint32_t exitv = (uint32_t)(nxt - 32) | 0x100u;
            st[rel] = (uint16_t)((nxt >= 32) ? exitv : cont);
        }
        // pack exit bytes of entries 0..15 for comp16
        #pragma unroll
        for (int w = 0; w < 4; ++w) {
            uint32_t e0 = st[w * 4 + 0] & 0xFFu, e1 = st[w * 4 + 1] & 0xFFu,
                     e2 = st[w * 4 + 2] & 0xFFu, e3 = st[w * 4 + 3] & 0xFFu;
            exitf32[c * 4 + w] = e0 | (e1 << 8) | (e2 << 16) | (e3 << 24);
        }
    }
    __syncthreads();                     // b3

    // ---- S: wave-0 mega-phase: fn scan -> entries, counts (from st), pbases, P ----
    if (tid < 64) {
        const uint4* xf4 = (const uint4*)exitf32;
        uint4 f0 = xf4[tid * 4], f1 = xf4[tid * 4 + 1],
              f2 = xf4[tid * 4 + 2], f3 = xf4[tid * 4 + 3];
        uint4 g = comp16(f1, f0);
        g = comp16(f2, g);
        g = comp16(f3, g);
        #pragma unroll
        for (int d = 1; d < 64; d <<= 1) {
            uint4 o;
            o.x = (uint32_t)__shfl_up((int)g.x, d);
            o.y = (uint32_t)__shfl_up((int)g.y, d);
            o.z = (uint32_t)__shfl_up((int)g.z, d);
            o.w = (uint32_t)__shfl_up((int)g.w, d);
            if (tid >= d) g = comp16(g, o);
        }
        uint4 E;
        E.x = (uint32_t)__shfl_up((int)g.x, 1);
        E.y = (uint32_t)__shfl_up((int)g.y, 1);
        E.z = (uint32_t)__shfl_up((int)g.z, 1);
        E.w = (uint32_t)__shfl_up((int)g.w, 1);
        if (tid == 0) E = make_uint4(0x03020100u, 0x07060504u, 0x0B0A0908u, 0x0F0E0D0Cu);
        uint32_t e0 = E.x & 255u;
        uint32_t e1 = bsel16(f0, e0);
        uint32_t e2 = bsel16(f1, e1);
        uint32_t e3 = bsel16(f2, e2);
        entry_s[tid * 4 + 0] = (uint8_t)e0;
        entry_s[tid * 4 + 1] = (uint8_t)e1;
        entry_s[tid * 4 + 2] = (uint8_t)e2;
        entry_s[tid * 4 + 3] = (uint8_t)e3;
        int c0 = (int)(st_l[(tid * 4 + 0) * STS + (int)e0] >> 8);
        int c1 = (int)(st_l[(tid * 4 + 1) * STS + (int)e1] >> 8);
        int c2 = (int)(st_l[(tid * 4 + 2) * STS + (int)e2] >> 8);
        int c3 = (int)(st_l[(tid * 4 + 3) * STS + (int)e3] >> 8);
        int s = c0 + c1 + c2 + c3;
        int incl = s;
        #pragma unroll
        for (int d = 1; d < 64; d <<= 1) { int o = __shfl_up(incl, d); if (tid >= d) incl += o; }
        int excl = incl - s;
        pbase_s[tid * 4 + 0] = (uint16_t)excl;
        pbase_s[tid * 4 + 1] = (uint16_t)(excl + c0);
        pbase_s[tid * 4 + 2] = (uint16_t)(excl + c0 + c1);
        pbase_s[tid * 4 + 3] = (uint16_t)(excl + c0 + c1 + c2);
        if (tid == 63) S_s[0] = incl;    // total P
    }
    __syncthreads();                     // b4

    // ---- X: expand chunks (bitmap walk) + sentinel fill, disjoint ranges ----
    if (tid < NCH) {
        int pb = (int)pbase_s[tid];
        int p = tid * 32 + (int)entry_s[tid];
        const int lim = tid * 32 + 32;
        while (p < lim) {
            starts_s[pb++] = (uint16_t)p;
            p += psize(stopb, p);
        }
    }
    {
        const int P = S_s[0];
        for (int i = P + tid; i < 4098; i += NT) starts_s[i] = (uint16_t)SEQ;
    }
    __syncthreads();                     // b5

    // ---- G: emit this half; 4-lane groups, alignbit extraction (proven R8) ----
    {
        int* outp = out + (size_t)b * (MAXP * 16);
        int* outm = out + (size_t)NB * MAXP * 16 + (size_t)b * MAXP;
        const int j = tid & 3;
        #pragma unroll
        for (int it = 0; it < (MAXP / RED) / (NT / 4); ++it) {   // 16 passes
            const int p = qc * (MAXP / RED) + it * (NT / 4) + (tid >> 2);
            const int st = (int)starts_s[p];
            const int sz = (int)starts_s[p + 1] - st;            // 0..16 (0 when p>=P)
            const int base = (st >> 2) + j;
            const uint32_t sh = (uint32_t)(st & 3) * 8u;
            uint32_t lo = tok32[base], hi = tok32[base + 1];
            uint32_t pk = (uint32_t)((((uint64_t)hi << 32) | lo) >> sh);
            int rem = sz - 4 * j;
            rem = (rem < 0) ? 0 : (rem > 4 ? 4 : rem);
            pk &= (uint32_t)((1ULL << (8 * rem)) - 1ULL);
            ((int4*)outp)[(size_t)p * 4 + j] =
                make_int4((int)(pk & 255u), (int)((pk >> 8) & 255u),
                          (int)((pk >> 16) & 255u), (int)(pk >> 24));
        }
        #pragma unroll
        for (int i = 0; i < (MAXP / RED) / NT; ++i) {            // 4 passes of masks
            const int p = qc * (MAXP / RED) + i * NT + tid;
            outm[p] = ((int)starts_s[p] < SEQ) ? 1 : 0;
        }
    }
}

extern "C" void kernel_launch(void* const* d_in, const int* in_sizes, int n_in,
                              void* d_out, int out_size, void* d_ws, size_t ws_size,
                              hipStream_t stream) {
    const int* tokens = (const int*)d_in[0];
    int* out = (int*)d_out;
    ep_fused<<<dim3(NB * RED), dim3(NT), 0, stream>>>(tokens, out);
}

// Round 12
// 21.032 us; speedup vs baseline: 1.8065x; 1.0210x over previous
//
#include <hip/hip_runtime.h>
#include <stdint.h>

#define SEQ  8192
#define NB   128
#define MAXP 4096
#define NT   512
#define RED  2                     // blocks per sequence (grid = 256 = 1 block/CU)
#define NCH  256                   // 32-wide chunks per sequence

__device__ __forceinline__ bool haszero8(uint64_t v) {
    return ((v - 0x0101010101010101ULL) & ~v & 0x8080808080808080ULL) != 0ULL;
}
__device__ __forceinline__ bool distinct8(uint64_t w) {
    uint64_t r1 = (w >> 8)  | (w << 56);
    uint64_t r2 = (w >> 16) | (w << 48);
    uint64_t r3 = (w >> 24) | (w << 40);
    uint64_t r4 = (w >> 32) | (w << 32);
    return !(haszero8(w ^ r1) | haszero8(w ^ r2) | haszero8(w ^ r3) | haszero8(w ^ r4));
}
__device__ __forceinline__ uint32_t pack4(int4 v) {
    return (uint32_t)(v.x & 255) | ((uint32_t)(v.y & 255) << 8) |
           ((uint32_t)(v.z & 255) << 16) | ((uint32_t)(v.w & 255) << 24);
}
__device__ __forceinline__ uint32_t bsel16(uint4 f, uint32_t b) {
    uint32_t w01 = (b & 4u) ? f.y : f.x;
    uint32_t w23 = (b & 4u) ? f.w : f.z;
    uint32_t w   = (b & 8u) ? w23 : w01;
    return (w >> ((b & 3u) << 3)) & 255u;
}
// byte pack: {a.b2,a.b0,b.b2,b.b0} -> one word (exit-byte table)
__device__ __forceinline__ uint32_t packexit(uint32_t pa, uint32_t pb) {
#if __has_builtin(__builtin_amdgcn_perm)
    return __builtin_amdgcn_perm(pb, pa, 0x06040200u);
#else
    return (pa & 0xFFu) | (((pa >> 16) & 0xFFu) << 8) |
           ((pb & 0xFFu) << 16) | (((pb >> 16) & 0xFFu) << 24);
#endif
}
// r.byte[i] = g.byte[f.byte[i]]  (byte values in [0,16)) -- proven rounds 5-11
__device__ __forceinline__ uint4 comp16(uint4 g, uint4 f) {
    uint4 r;
#if __has_builtin(__builtin_amdgcn_perm)
    #define C16W(fw, out) do { \
        uint32_t sel = (fw) & 0x07070707u; \
        uint32_t lo = __builtin_amdgcn_perm(g.y, g.x, sel); \
        uint32_t hi = __builtin_amdgcn_perm(g.w, g.z, sel); \
        uint32_t m = ((fw) & 0x08080808u) >> 3; m = (m << 8) - m; \
        out = (lo & ~m) | (hi & m); } while (0)
    C16W(f.x, r.x); C16W(f.y, r.y); C16W(f.z, r.z); C16W(f.w, r.w);
    #undef C16W
#else
    #define C16B(fw, out) do { uint32_t o = 0; \
        o |= bsel16(g, (fw) & 15u); \
        o |= bsel16(g, ((fw) >> 8) & 15u) << 8; \
        o |= bsel16(g, ((fw) >> 16) & 15u) << 16; \
        o |= bsel16(g, ((fw) >> 24) & 15u) << 24; \
        out = o; } while (0)
    C16B(f.x, r.x); C16B(f.y, r.y); C16B(f.z, r.z); C16B(f.w, r.w);
    #undef C16B
#endif
    return r;
}
// proven size rule, reading the stop bitmap directly
__device__ __forceinline__ int psize(const uint32_t* stopb, int p) {
    int bp = p + 2, w = bp >> 5;
    uint64_t comb = (uint64_t)stopb[w] | ((uint64_t)stopb[w + 1] << 32);
    uint32_t win14 = (uint32_t)(comb >> (bp & 31)) & 0x3FFFu;
    return win14 ? (2 + __builtin_ctz(win14)) : min(16, SEQ - p);
}

__global__ __launch_bounds__(NT) void ep_fused(const int* __restrict__ tokens,
                                               int* __restrict__ out) {
    __shared__ uint32_t tok32[2056];     // 8192 tokens u8-packed + 32B zero pad
    __shared__ uint32_t stopb[258];
    __shared__ uint32_t st16[NCH * 9];   // per chunk: st[0..15] packed (8 words, stride 9)
    __shared__ uint32_t exitf32[NCH * 4];
    __shared__ uint8_t  entry_s[NCH];
    __shared__ uint16_t pbase_s[NCH];
    __shared__ uint16_t starts_s[4100];
    __shared__ int S_s[2];               // 0: total P

    const int bx = blockIdx.x;
    const int b = bx >> 1, qc = bx & 1;  // sequence, emission half
    const int tid = threadIdx.x;

    // ---- A: coalesced load, pack tokens to u8 (proven) ----
    {
        const int4* t4 = (const int4*)(tokens + (size_t)b * SEQ);
        #pragma unroll
        for (int k = 0; k < 4; ++k) { int g = k * NT + tid; tok32[g] = pack4(t4[g]); }
        if (tid < 8) tok32[2048 + tid] = 0u;
        if (tid < 2) stopb[256 + tid] = 0u;
    }
    __syncthreads();                     // b1

    // ---- B: stop bits (proven; bounds-check hoisted to tid 511) ----
    {
        const int base = tid * 4;
        uint64_t win = (uint64_t)tok32[base] | ((uint64_t)tok32[base + 1] << 32);
        uint32_t bits = 0;
        #pragma unroll
        for (int k = 0; k < 4; ++k) {
            uint32_t nx = tok32[base + 2 + k];
            #pragma unroll
            for (int m = 0; m < 4; ++m) {
                if (distinct8(win)) bits |= (1u << (k * 4 + m));
                win = (win >> 8) | ((uint64_t)(nx & 255u) << 56);
                nx >>= 8;
            }
        }
        if (tid == NT - 1) bits &= 0x1FFu;       // j <= SEQ-8 for the tail thread
        uint32_t other = (uint32_t)__shfl_xor((int)bits, 1);
        if ((tid & 1) == 0) stopb[tid >> 1] = (bits & 0xFFFFu) | (other << 16);
    }
    __syncthreads();                     // b2

    // ---- T: per-chunk backward DP, register sliding window (same recursion) ----
    if (tid < NCH) {
        const int c = tid;
        const uint64_t W = (uint64_t)stopb[c] | ((uint64_t)stopb[c + 1] << 32);
        const int gb = c * 32;
        // pk = st[rel+2k+1] | st[rel+2k+2]<<16  (window of the 16 positions after rel)
        uint32_t p0 = 0, p1 = 0, p2 = 0, p3 = 0, p4 = 0, p5 = 0, p6 = 0, p7 = 0;
        #pragma unroll
        for (int rel = 31; rel >= 0; --rel) {
            uint32_t win14 = (uint32_t)(W >> (rel + 2)) & 0x3FFFu;
            int sz = win14 ? (2 + __builtin_ctz(win14)) : min(16, SEQ - (gb + rel));
            int nxt = rel + sz;
            uint32_t stv;
            if (nxt >= 32) {
                stv = (uint32_t)(nxt - 32) | 0x100u;
            } else {
                int s = sz - 1;                  // 0..15; selected value always defined
                uint32_t q01 = (s & 2) ? p1 : p0;
                uint32_t q23 = (s & 2) ? p3 : p2;
                uint32_t q45 = (s & 2) ? p5 : p4;
                uint32_t q67 = (s & 2) ? p7 : p6;
                uint32_t qa  = (s & 4) ? q23 : q01;
                uint32_t qb  = (s & 4) ? q67 : q45;
                uint32_t q   = (s & 8) ? qb : qa;
                uint32_t sel = (s & 1) ? (q >> 16) : (q & 0xFFFFu);
                stv = sel + 0x100u;              // count+1, exit byte preserved
            }
            // slide window down by one position
            p7 = (p7 << 16) | (p6 >> 16);
            p6 = (p6 << 16) | (p5 >> 16);
            p5 = (p5 << 16) | (p4 >> 16);
            p4 = (p4 << 16) | (p3 >> 16);
            p3 = (p3 << 16) | (p2 >> 16);
            p2 = (p2 << 16) | (p1 >> 16);
            p1 = (p1 << 16) | (p0 >> 16);
            p0 = (p0 << 16) | stv;
        }
        // now p0..p7 = st[0..15] packed; publish for S + exit-byte table
        uint32_t* st = st16 + c * 9;
        st[0] = p0; st[1] = p1; st[2] = p2; st[3] = p3;
        st[4] = p4; st[5] = p5; st[6] = p6; st[7] = p7;
        exitf32[c * 4 + 0] = packexit(p0, p1);
        exitf32[c * 4 + 1] = packexit(p2, p3);
        exitf32[c * 4 + 2] = packexit(p4, p5);
        exitf32[c * 4 + 3] = packexit(p6, p7);
    }
    __syncthreads();                     // b3

    // ---- S: wave-0 mega-phase: fn scan -> entries, counts (from st16), pbases, P ----
    if (tid < 64) {
        const uint4* xf4 = (const uint4*)exitf32;
        uint4 f0 = xf4[tid * 4], f1 = xf4[tid * 4 + 1],
              f2 = xf4[tid * 4 + 2], f3 = xf4[tid * 4 + 3];
        uint4 g = comp16(f1, f0);
        g = comp16(f2, g);
        g = comp16(f3, g);
        #pragma unroll
        for (int d = 1; d < 64; d <<= 1) {
            uint4 o;
            o.x = (uint32_t)__shfl_up((int)g.x, d);
            o.y = (uint32_t)__shfl_up((int)g.y, d);
            o.z = (uint32_t)__shfl_up((int)g.z, d);
            o.w = (uint32_t)__shfl_up((int)g.w, d);
            if (tid >= d) g = comp16(g, o);
        }
        uint4 E;
        E.x = (uint32_t)__shfl_up((int)g.x, 1);
        E.y = (uint32_t)__shfl_up((int)g.y, 1);
        E.z = (uint32_t)__shfl_up((int)g.z, 1);
        E.w = (uint32_t)__shfl_up((int)g.w, 1);
        if (tid == 0) E = make_uint4(0x03020100u, 0x07060504u, 0x0B0A0908u, 0x0F0E0D0Cu);
        uint32_t e0 = E.x & 255u;
        uint32_t e1 = bsel16(f0, e0);
        uint32_t e2 = bsel16(f1, e1);
        uint32_t e3 = bsel16(f2, e2);
        entry_s[tid * 4 + 0] = (uint8_t)e0;
        entry_s[tid * 4 + 1] = (uint8_t)e1;
        entry_s[tid * 4 + 2] = (uint8_t)e2;
        entry_s[tid * 4 + 3] = (uint8_t)e3;
        uint32_t w0 = st16[(tid * 4 + 0) * 9 + (e0 >> 1)];
        uint32_t w1 = st16[(tid * 4 + 1) * 9 + (e1 >> 1)];
        uint32_t w2 = st16[(tid * 4 + 2) * 9 + (e2 >> 1)];
        uint32_t w3 = st16[(tid * 4 + 3) * 9 + (e3 >> 1)];
        int c0 = (int)(((w0 >> ((e0 & 1) * 16)) & 0xFFFFu) >> 8);
        int c1 = (int)(((w1 >> ((e1 & 1) * 16)) & 0xFFFFu) >> 8);
        int c2 = (int)(((w2 >> ((e2 & 1) * 16)) & 0xFFFFu) >> 8);
        int c3 = (int)(((w3 >> ((e3 & 1) * 16)) & 0xFFFFu) >> 8);
        int s = c0 + c1 + c2 + c3;
        int incl = s;
        #pragma unroll
        for (int d = 1; d < 64; d <<= 1) { int o = __shfl_up(incl, d); if (tid >= d) incl += o; }
        int excl = incl - s;
        pbase_s[tid * 4 + 0] = (uint16_t)excl;
        pbase_s[tid * 4 + 1] = (uint16_t)(excl + c0);
        pbase_s[tid * 4 + 2] = (uint16_t)(excl + c0 + c1);
        pbase_s[tid * 4 + 3] = (uint16_t)(excl + c0 + c1 + c2);
        if (tid == 63) S_s[0] = incl;    // total P
    }
    __syncthreads();                     // b4

    // ---- X: expand chunks (bitmap walk) + sentinel fill, disjoint ranges ----
    if (tid < NCH) {
        int pb = (int)pbase_s[tid];
        int p = tid * 32 + (int)entry_s[tid];
        const int lim = tid * 32 + 32;
        while (p < lim) {
            starts_s[pb++] = (uint16_t)p;
            p += psize(stopb, p);
        }
    }
    {
        const int P = S_s[0];
        for (int i = P + tid; i < 4098; i += NT) starts_s[i] = (uint16_t)SEQ;
    }
    __syncthreads();                     // b5

    // ---- G: emit this half; 4-lane groups, alignbit extraction (proven R8) ----
    {
        int* outp = out + (size_t)b * (MAXP * 16);
        int* outm = out + (size_t)NB * MAXP * 16 + (size_t)b * MAXP;
        const int j = tid & 3;
        #pragma unroll
        for (int it = 0; it < (MAXP / RED) / (NT / 4); ++it) {   // 16 passes
            const int p = qc * (MAXP / RED) + it * (NT / 4) + (tid >> 2);
            const int st = (int)starts_s[p];
            const int sz = (int)starts_s[p + 1] - st;            // 0..16 (0 when p>=P)
            const int base = (st >> 2) + j;
            const uint32_t sh = (uint32_t)(st & 3) * 8u;
            uint32_t lo = tok32[base], hi = tok32[base + 1];
            uint32_t pk = (uint32_t)((((uint64_t)hi << 32) | lo) >> sh);
            int rem = sz - 4 * j;
            rem = (rem < 0) ? 0 : (rem > 4 ? 4 : rem);
            pk &= (uint32_t)((1ULL << (8 * rem)) - 1ULL);
            ((int4*)outp)[(size_t)p * 4 + j] =
                make_int4((int)(pk & 255u), (int)((pk >> 8) & 255u),
                          (int)((pk >> 16) & 255u), (int)(pk >> 24));
        }
        {   // masks: one int4 pass (2048 masks / block-half)
            const int p4 = qc * (MAXP / RED) + tid * 4;
            const uint32_t* s32 = (const uint32_t*)starts_s;
            uint32_t a = s32[p4 >> 1], bw = s32[(p4 >> 1) + 1];
            ((int4*)(outm + qc * (MAXP / RED)))[tid] =
                make_int4((a & 0xFFFFu) < SEQ ? 1 : 0, (a >> 16) < SEQ ? 1 : 0,
                          (bw & 0xFFFFu) < SEQ ? 1 : 0, (bw >> 16) < SEQ ? 1 : 0);
        }
    }
}

extern "C" void kernel_launch(void* const* d_in, const int* in_sizes, int n_in,
                              void* d_out, int out_size, void* d_ws, size_t ws_size,
                              hipStream_t stream) {
    const int* tokens = (const int*)d_in[0];
    int* out = (int*)d_out;
    ep_fused<<<dim3(NB * RED), dim3(NT), 0, stream>>>(tokens, out);
}

// Round 13
// 20.577 us; speedup vs baseline: 1.8465x; 1.0221x over previous
//
#include <hip/hip_runtime.h>
#include <stdint.h>

#define SEQ  8192
#define NB   128
#define MAXP 4096
#define NT   1024
#define RED  2                     // blocks per sequence (grid = 256 = 1 block/CU)
#define NCH  256                   // 32-wide chunks per sequence

__device__ __forceinline__ bool haszero8(uint64_t v) {
    return ((v - 0x0101010101010101ULL) & ~v & 0x8080808080808080ULL) != 0ULL;
}
__device__ __forceinline__ bool distinct8(uint64_t w) {
    uint64_t r1 = (w >> 8)  | (w << 56);
    uint64_t r2 = (w >> 16) | (w << 48);
    uint64_t r3 = (w >> 24) | (w << 40);
    uint64_t r4 = (w >> 32) | (w << 32);
    return !(haszero8(w ^ r1) | haszero8(w ^ r2) | haszero8(w ^ r3) | haszero8(w ^ r4));
}
__device__ __forceinline__ uint32_t pack4(int4 v) {
    return (uint32_t)(v.x & 255) | ((uint32_t)(v.y & 255) << 8) |
           ((uint32_t)(v.z & 255) << 16) | ((uint32_t)(v.w & 255) << 24);
}
__device__ __forceinline__ uint32_t bsel16(uint4 f, uint32_t b) {
    uint32_t w01 = (b & 4u) ? f.y : f.x;
    uint32_t w23 = (b & 4u) ? f.w : f.z;
    uint32_t w   = (b & 8u) ? w23 : w01;
    return (w >> ((b & 3u) << 3)) & 255u;
}
// byte pack: {a.b2,a.b0,b.b2,b.b0} -> one word (exit-byte table)
__device__ __forceinline__ uint32_t packexit(uint32_t pa, uint32_t pb) {
#if __has_builtin(__builtin_amdgcn_perm)
    return __builtin_amdgcn_perm(pb, pa, 0x06040200u);
#else
    return (pa & 0xFFu) | (((pa >> 16) & 0xFFu) << 8) |
           ((pb & 0xFFu) << 16) | (((pb >> 16) & 0xFFu) << 24);
#endif
}
// r.byte[i] = g.byte[f.byte[i]]  (byte values in [0,16)) -- proven rounds 5-12
__device__ __forceinline__ uint4 comp16(uint4 g, uint4 f) {
    uint4 r;
#if __has_builtin(__builtin_amdgcn_perm)
    #define C16W(fw, out) do { \
        uint32_t sel = (fw) & 0x07070707u; \
        uint32_t lo = __builtin_amdgcn_perm(g.y, g.x, sel); \
        uint32_t hi = __builtin_amdgcn_perm(g.w, g.z, sel); \
        uint32_t m = ((fw) & 0x08080808u) >> 3; m = (m << 8) - m; \
        out = (lo & ~m) | (hi & m); } while (0)
    C16W(f.x, r.x); C16W(f.y, r.y); C16W(f.z, r.z); C16W(f.w, r.w);
    #undef C16W
#else
    #define C16B(fw, out) do { uint32_t o = 0; \
        o |= bsel16(g, (fw) & 15u); \
        o |= bsel16(g, ((fw) >> 8) & 15u) << 8; \
        o |= bsel16(g, ((fw) >> 16) & 15u) << 16; \
        o |= bsel16(g, ((fw) >> 24) & 15u) << 24; \
        out = o; } while (0)
    C16B(f.x, r.x); C16B(f.y, r.y); C16B(f.z, r.z); C16B(f.w, r.w);
    #undef C16B
#endif
    return r;
}

__global__ __launch_bounds__(NT) void ep_fused(const int* __restrict__ tokens,
                                               int* __restrict__ out) {
    __shared__ uint32_t tok32[2056];     // 8192 tokens u8-packed + 32B zero pad
    __shared__ uint32_t stopb[258];
    __shared__ uint32_t st16[NCH * 9];   // per chunk: st[0..15] packed (8 words, stride 9)
    __shared__ uint32_t exitf32[NCH * 4];
    __shared__ uint8_t  entry_s[NCH];
    __shared__ uint16_t pbase_s[NCH];
    __shared__ uint16_t starts_s[4100];
    __shared__ int S_s[2];               // 0: total P

    const int bx = blockIdx.x;
    const int b = bx >> 1, qc = bx & 1;  // sequence, emission half
    const int tid = threadIdx.x;

    // ---- A: coalesced load, pack tokens to u8 (proven) ----
    {
        const int4* t4 = (const int4*)(tokens + (size_t)b * SEQ);
        #pragma unroll
        for (int k = 0; k < 2; ++k) { int g = k * NT + tid; tok32[g] = pack4(t4[g]); }
        if (tid < 8) tok32[2048 + tid] = 0u;
        if (tid < 2) stopb[256 + tid] = 0u;
    }
    __syncthreads();                     // b1

    // ---- B: stop bits, 8 windows/thread; pack 4 threads -> 1 word via shfl ----
    {
        const int base = tid * 2;
        uint64_t win = (uint64_t)tok32[base] | ((uint64_t)tok32[base + 1] << 32);
        uint32_t nx0 = tok32[base + 2], nx1 = tok32[base + 3];
        uint32_t bits = 0;
        #pragma unroll
        for (int m = 0; m < 4; ++m) {
            if (distinct8(win)) bits |= (1u << m);
            win = (win >> 8) | ((uint64_t)(nx0 & 255u) << 56);
            nx0 >>= 8;
        }
        #pragma unroll
        for (int m = 4; m < 8; ++m) {
            if (distinct8(win)) bits |= (1u << m);
            win = (win >> 8) | ((uint64_t)(nx1 & 255u) << 56);
            nx1 >>= 8;
        }
        if (tid == NT - 1) bits &= 0x1u;             // only j=8184 valid on tail thread
        uint32_t a = bits | ((uint32_t)__shfl_xor((int)bits, 1) << 8);
        uint32_t w32 = a | ((uint32_t)__shfl_xor((int)a, 2) << 16);
        if ((tid & 3) == 0) stopb[tid >> 2] = w32;
    }
    __syncthreads();                     // b2

    // ---- T: per-chunk backward DP, register sliding window (proven R12) ----
    if (tid < NCH) {
        const int c = tid;
        const uint64_t W = (uint64_t)stopb[c] | ((uint64_t)stopb[c + 1] << 32);
        const int gb = c * 32;
        uint32_t p0 = 0, p1 = 0, p2 = 0, p3 = 0, p4 = 0, p5 = 0, p6 = 0, p7 = 0;
        #pragma unroll
        for (int rel = 31; rel >= 0; --rel) {
            uint32_t win14 = (uint32_t)(W >> (rel + 2)) & 0x3FFFu;
            int sz = win14 ? (2 + __builtin_ctz(win14)) : min(16, SEQ - (gb + rel));
            int nxt = rel + sz;
            uint32_t stv;
            if (nxt >= 32) {
                stv = (uint32_t)(nxt - 32) | 0x100u;
            } else {
                int s = sz - 1;
                uint32_t q01 = (s & 2) ? p1 : p0;
                uint32_t q23 = (s & 2) ? p3 : p2;
                uint32_t q45 = (s & 2) ? p5 : p4;
                uint32_t q67 = (s & 2) ? p7 : p6;
                uint32_t qa  = (s & 4) ? q23 : q01;
                uint32_t qb  = (s & 4) ? q67 : q45;
                uint32_t q   = (s & 8) ? qb : qa;
                uint32_t sel = (s & 1) ? (q >> 16) : (q & 0xFFFFu);
                stv = sel + 0x100u;
            }
            p7 = (p7 << 16) | (p6 >> 16);
            p6 = (p6 << 16) | (p5 >> 16);
            p5 = (p5 << 16) | (p4 >> 16);
            p4 = (p4 << 16) | (p3 >> 16);
            p3 = (p3 << 16) | (p2 >> 16);
            p2 = (p2 << 16) | (p1 >> 16);
            p1 = (p1 << 16) | (p0 >> 16);
            p0 = (p0 << 16) | stv;
        }
        uint32_t* st = st16 + c * 9;
        st[0] = p0; st[1] = p1; st[2] = p2; st[3] = p3;
        st[4] = p4; st[5] = p5; st[6] = p6; st[7] = p7;
        exitf32[c * 4 + 0] = packexit(p0, p1);
        exitf32[c * 4 + 1] = packexit(p2, p3);
        exitf32[c * 4 + 2] = packexit(p4, p5);
        exitf32[c * 4 + 3] = packexit(p6, p7);
    }
    __syncthreads();                     // b3

    // ---- S: wave-0 mega-phase: fn scan -> entries, counts, pbases, P (proven) ----
    if (tid < 64) {
        const uint4* xf4 = (const uint4*)exitf32;
        uint4 f0 = xf4[tid * 4], f1 = xf4[tid * 4 + 1],
              f2 = xf4[tid * 4 + 2], f3 = xf4[tid * 4 + 3];
        uint4 g = comp16(f1, f0);
        g = comp16(f2, g);
        g = comp16(f3, g);
        #pragma unroll
        for (int d = 1; d < 64; d <<= 1) {
            uint4 o;
            o.x = (uint32_t)__shfl_up((int)g.x, d);
            o.y = (uint32_t)__shfl_up((int)g.y, d);
            o.z = (uint32_t)__shfl_up((int)g.z, d);
            o.w = (uint32_t)__shfl_up((int)g.w, d);
            if (tid >= d) g = comp16(g, o);
        }
        uint4 E;
        E.x = (uint32_t)__shfl_up((int)g.x, 1);
        E.y = (uint32_t)__shfl_up((int)g.y, 1);
        E.z = (uint32_t)__shfl_up((int)g.z, 1);
        E.w = (uint32_t)__shfl_up((int)g.w, 1);
        if (tid == 0) E = make_uint4(0x03020100u, 0x07060504u, 0x0B0A0908u, 0x0F0E0D0Cu);
        uint32_t e0 = E.x & 255u;
        uint32_t e1 = bsel16(f0, e0);
        uint32_t e2 = bsel16(f1, e1);
        uint32_t e3 = bsel16(f2, e2);
        entry_s[tid * 4 + 0] = (uint8_t)e0;
        entry_s[tid * 4 + 1] = (uint8_t)e1;
        entry_s[tid * 4 + 2] = (uint8_t)e2;
        entry_s[tid * 4 + 3] = (uint8_t)e3;
        uint32_t w0 = st16[(tid * 4 + 0) * 9 + (e0 >> 1)];
        uint32_t w1 = st16[(tid * 4 + 1) * 9 + (e1 >> 1)];
        uint32_t w2 = st16[(tid * 4 + 2) * 9 + (e2 >> 1)];
        uint32_t w3 = st16[(tid * 4 + 3) * 9 + (e3 >> 1)];
        int c0 = (int)(((w0 >> ((e0 & 1) * 16)) & 0xFFFFu) >> 8);
        int c1 = (int)(((w1 >> ((e1 & 1) * 16)) & 0xFFFFu) >> 8);
        int c2 = (int)(((w2 >> ((e2 & 1) * 16)) & 0xFFFFu) >> 8);
        int c3 = (int)(((w3 >> ((e3 & 1) * 16)) & 0xFFFFu) >> 8);
        int s = c0 + c1 + c2 + c3;
        int incl = s;
        #pragma unroll
        for (int d = 1; d < 64; d <<= 1) { int o = __shfl_up(incl, d); if (tid >= d) incl += o; }
        int excl = incl - s;
        pbase_s[tid * 4 + 0] = (uint16_t)excl;
        pbase_s[tid * 4 + 1] = (uint16_t)(excl + c0);
        pbase_s[tid * 4 + 2] = (uint16_t)(excl + c0 + c1);
        pbase_s[tid * 4 + 3] = (uint16_t)(excl + c0 + c1 + c2);
        if (tid == 63) S_s[0] = incl;    // total P
    }
    __syncthreads();                     // b4

    // ---- X: expand chunks via register walk + sentinel fill ----
    if (tid < NCH) {
        const int c = tid;
        const uint64_t W = (uint64_t)stopb[c] | ((uint64_t)stopb[c + 1] << 32);
        const int gb = c * 32;
        int pb = (int)pbase_s[c];
        int rel = (int)entry_s[c];
        while (rel < 32) {
            starts_s[pb++] = (uint16_t)(gb + rel);
            uint32_t win14 = (uint32_t)(W >> (rel + 2)) & 0x3FFFu;
            rel += win14 ? (2 + __builtin_ctz(win14)) : min(16, SEQ - (gb + rel));
        }
    }
    {
        const int P = S_s[0];
        for (int i = P + tid; i < 4098; i += NT) starts_s[i] = (uint16_t)SEQ;
    }
    __syncthreads();                     // b5

    // ---- G: emit this half; 4-lane groups, alignbit extraction (proven R8) ----
    {
        int* outp = out + (size_t)b * (MAXP * 16);
        int* outm = out + (size_t)NB * MAXP * 16 + (size_t)b * MAXP;
        const int j = tid & 3;
        #pragma unroll
        for (int it = 0; it < (MAXP / RED) / (NT / 4); ++it) {   // 8 passes
            const int p = qc * (MAXP / RED) + it * (NT / 4) + (tid >> 2);
            const int st = (int)starts_s[p];
            const int sz = (int)starts_s[p + 1] - st;            // 0..16 (0 when p>=P)
            const int base = (st >> 2) + j;
            const uint32_t sh = (uint32_t)(st & 3) * 8u;
            uint32_t lo = tok32[base], hi = tok32[base + 1];
            uint32_t pk = (uint32_t)((((uint64_t)hi << 32) | lo) >> sh);
            int rem = sz - 4 * j;
            rem = (rem < 0) ? 0 : (rem > 4 ? 4 : rem);
            pk &= (uint32_t)((1ULL << (8 * rem)) - 1ULL);
            ((int4*)outp)[(size_t)p * 4 + j] =
                make_int4((int)(pk & 255u), (int)((pk >> 8) & 255u),
                          (int)((pk >> 16) & 255u), (int)(pk >> 24));
        }
        if (tid < (MAXP / RED) / 4) {    // masks: one int4 pass (512 threads)
            const int p4 = qc * (MAXP / RED) + tid * 4;
            const uint32_t* s32 = (const uint32_t*)starts_s;
            uint32_t a = s32[p4 >> 1], bw = s32[(p4 >> 1) + 1];
            ((int4*)(outm + qc * (MAXP / RED)))[tid] =
                make_int4((a & 0xFFFFu) < SEQ ? 1 : 0, (a >> 16) < SEQ ? 1 : 0,
                          (bw & 0xFFFFu) < SEQ ? 1 : 0, (bw >> 16) < SEQ ? 1 : 0);
        }
    }
}

extern "C" void kernel_launch(void* const* d_in, const int* in_sizes, int n_in,
                              void* d_out, int out_size, void* d_ws, size_t ws_size,
                              hipStream_t stream) {
    const int* tokens = (const int*)d_in[0];
    int* out = (int*)d_out;
    ep_fused<<<dim3(NB * RED), dim3(NT), 0, stream>>>(tokens, out);
}

// Round 15
// 18.899 us; speedup vs baseline: 2.0104x; 1.0888x over previous
//
#include <hip/hip_runtime.h>
#include <stdint.h>

#define SEQ  8192
#define NB   128
#define MAXP 4096
#define NT   1024
#define RED  2                     // blocks per sequence (grid = 256 = 1 block/CU)
#define NCH  256                   // 32-wide chunks per sequence

typedef int  i32x4 __attribute__((ext_vector_type(4)));   // native vec for nt-store

__device__ __forceinline__ bool haszero8(uint64_t v) {
    return ((v - 0x0101010101010101ULL) & ~v & 0x8080808080808080ULL) != 0ULL;
}
__device__ __forceinline__ bool distinct8(uint64_t w) {
    uint64_t r1 = (w >> 8)  | (w << 56);
    uint64_t r2 = (w >> 16) | (w << 48);
    uint64_t r3 = (w >> 24) | (w << 40);
    uint64_t r4 = (w >> 32) | (w << 32);
    return !(haszero8(w ^ r1) | haszero8(w ^ r2) | haszero8(w ^ r3) | haszero8(w ^ r4));
}
__device__ __forceinline__ uint32_t pack4(int4 v) {
    return (uint32_t)(v.x & 255) | ((uint32_t)(v.y & 255) << 8) |
           ((uint32_t)(v.z & 255) << 16) | ((uint32_t)(v.w & 255) << 24);
}
__device__ __forceinline__ uint32_t bsel16(uint4 f, uint32_t b) {
    uint32_t w01 = (b & 4u) ? f.y : f.x;
    uint32_t w23 = (b & 4u) ? f.w : f.z;
    uint32_t w   = (b & 8u) ? w23 : w01;
    return (w >> ((b & 3u) << 3)) & 255u;
}
// byte pack: {a.b2,a.b0,b.b2,b.b0} -> one word (exit-byte table)
__device__ __forceinline__ uint32_t packexit(uint32_t pa, uint32_t pb) {
#if __has_builtin(__builtin_amdgcn_perm)
    return __builtin_amdgcn_perm(pb, pa, 0x06040200u);
#else
    return (pa & 0xFFu) | (((pa >> 16) & 0xFFu) << 8) |
           ((pb & 0xFFu) << 16) | (((pb >> 16) & 0xFFu) << 24);
#endif
}
// r.byte[i] = g.byte[f.byte[i]]  (byte values in [0,16)) -- proven rounds 5-13
__device__ __forceinline__ uint4 comp16(uint4 g, uint4 f) {
    uint4 r;
#if __has_builtin(__builtin_amdgcn_perm)
    #define C16W(fw, out) do { \
        uint32_t sel = (fw) & 0x07070707u; \
        uint32_t lo = __builtin_amdgcn_perm(g.y, g.x, sel); \
        uint32_t hi = __builtin_amdgcn_perm(g.w, g.z, sel); \
        uint32_t m = ((fw) & 0x08080808u) >> 3; m = (m << 8) - m; \
        out = (lo & ~m) | (hi & m); } while (0)
    C16W(f.x, r.x); C16W(f.y, r.y); C16W(f.z, r.z); C16W(f.w, r.w);
    #undef C16W
#else
    #define C16B(fw, out) do { uint32_t o = 0; \
        o |= bsel16(g, (fw) & 15u); \
        o |= bsel16(g, ((fw) >> 8) & 15u) << 8; \
        o |= bsel16(g, ((fw) >> 16) & 15u) << 16; \
        o |= bsel16(g, ((fw) >> 24) & 15u) << 24; \
        out = o; } while (0)
    C16B(f.x, r.x); C16B(f.y, r.y); C16B(f.z, r.z); C16B(f.w, r.w);
    #undef C16B
#endif
    return r;
}

__global__ __launch_bounds__(NT) void ep_fused(const int* __restrict__ tokens,
                                               int* __restrict__ out) {
    __shared__ uint32_t tok32[2056];     // 8192 tokens u8-packed + 32B zero pad
    __shared__ uint32_t stopb[258];
    __shared__ uint32_t st16[NCH * 9];   // per chunk: st[0..15] packed (8 words, stride 9)
    __shared__ uint32_t exitf32[NCH * 4];
    __shared__ uint8_t  entry_s[NCH];
    __shared__ uint16_t pbase_s[NCH];
    __shared__ uint16_t starts_s[4100];
    __shared__ int S_s[2];               // 0: total P

    const int bx = blockIdx.x;
    const int b = bx >> 1, qc = bx & 1;  // sequence, emission half
    const int tid = threadIdx.x;

    // ---- A: coalesced load, pack tokens to u8 (proven) ----
    {
        const int4* t4 = (const int4*)(tokens + (size_t)b * SEQ);
        #pragma unroll
        for (int k = 0; k < 2; ++k) { int g = k * NT + tid; tok32[g] = pack4(t4[g]); }
        if (tid < 8) tok32[2048 + tid] = 0u;
        if (tid < 2) stopb[256 + tid] = 0u;
    }
    __syncthreads();                     // b1

    // ---- B: stop bits, 8 windows/thread; pack 4 threads -> 1 word via shfl ----
    {
        const int base = tid * 2;
        uint64_t win = (uint64_t)tok32[base] | ((uint64_t)tok32[base + 1] << 32);
        uint32_t nx0 = tok32[base + 2], nx1 = tok32[base + 3];
        uint32_t bits = 0;
        #pragma unroll
        for (int m = 0; m < 4; ++m) {
            if (distinct8(win)) bits |= (1u << m);
            win = (win >> 8) | ((uint64_t)(nx0 & 255u) << 56);
            nx0 >>= 8;
        }
        #pragma unroll
        for (int m = 4; m < 8; ++m) {
            if (distinct8(win)) bits |= (1u << m);
            win = (win >> 8) | ((uint64_t)(nx1 & 255u) << 56);
            nx1 >>= 8;
        }
        if (tid == NT - 1) bits &= 0x1u;             // only j=8184 valid on tail thread
        uint32_t a = bits | ((uint32_t)__shfl_xor((int)bits, 1) << 8);
        uint32_t w32 = a | ((uint32_t)__shfl_xor((int)a, 2) << 16);
        if ((tid & 3) == 0) stopb[tid >> 2] = w32;
    }
    __syncthreads();                     // b2

    // ---- T: per-chunk backward DP, register sliding window (proven R12) ----
    if (tid < NCH) {
        const int c = tid;
        const uint64_t W = (uint64_t)stopb[c] | ((uint64_t)stopb[c + 1] << 32);
        const int gb = c * 32;
        uint32_t p0 = 0, p1 = 0, p2 = 0, p3 = 0, p4 = 0, p5 = 0, p6 = 0, p7 = 0;
        #pragma unroll
        for (int rel = 31; rel >= 0; --rel) {
            uint32_t win14 = (uint32_t)(W >> (rel + 2)) & 0x3FFFu;
            int sz = win14 ? (2 + __builtin_ctz(win14)) : min(16, SEQ - (gb + rel));
            int nxt = rel + sz;
            uint32_t stv;
            if (nxt >= 32) {
                stv = (uint32_t)(nxt - 32) | 0x100u;
            } else {
                int s = sz - 1;
                uint32_t q01 = (s & 2) ? p1 : p0;
                uint32_t q23 = (s & 2) ? p3 : p2;
                uint32_t q45 = (s & 2) ? p5 : p4;
                uint32_t q67 = (s & 2) ? p7 : p6;
                uint32_t qa  = (s & 4) ? q23 : q01;
                uint32_t qb  = (s & 4) ? q67 : q45;
                uint32_t q   = (s & 8) ? qb : qa;
                uint32_t sel = (s & 1) ? (q >> 16) : (q & 0xFFFFu);
                stv = sel + 0x100u;
            }
            p7 = (p7 << 16) | (p6 >> 16);
            p6 = (p6 << 16) | (p5 >> 16);
            p5 = (p5 << 16) | (p4 >> 16);
            p4 = (p4 << 16) | (p3 >> 16);
            p3 = (p3 << 16) | (p2 >> 16);
            p2 = (p2 << 16) | (p1 >> 16);
            p1 = (p1 << 16) | (p0 >> 16);
            p0 = (p0 << 16) | stv;
        }
        uint32_t* st = st16 + c * 9;
        st[0] = p0; st[1] = p1; st[2] = p2; st[3] = p3;
        st[4] = p4; st[5] = p5; st[6] = p6; st[7] = p7;
        exitf32[c * 4 + 0] = packexit(p0, p1);
        exitf32[c * 4 + 1] = packexit(p2, p3);
        exitf32[c * 4 + 2] = packexit(p4, p5);
        exitf32[c * 4 + 3] = packexit(p6, p7);
    }
    __syncthreads();                     // b3

    // ---- S: wave-0 mega-phase: fn scan -> entries, counts, pbases, P (proven) ----
    if (tid < 64) {
        const uint4* xf4 = (const uint4*)exitf32;
        uint4 f0 = xf4[tid * 4], f1 = xf4[tid * 4 + 1],
              f2 = xf4[tid * 4 + 2], f3 = xf4[tid * 4 + 3];
        uint4 g = comp16(f1, f0);
        g = comp16(f2, g);
        g = comp16(f3, g);
        #pragma unroll
        for (int d = 1; d < 64; d <<= 1) {
            uint4 o;
            o.x = (uint32_t)__shfl_up((int)g.x, d);
            o.y = (uint32_t)__shfl_up((int)g.y, d);
            o.z = (uint32_t)__shfl_up((int)g.z, d);
            o.w = (uint32_t)__shfl_up((int)g.w, d);
            if (tid >= d) g = comp16(g, o);
        }
        uint4 E;
        E.x = (uint32_t)__shfl_up((int)g.x, 1);
        E.y = (uint32_t)__shfl_up((int)g.y, 1);
        E.z = (uint32_t)__shfl_up((int)g.z, 1);
        E.w = (uint32_t)__shfl_up((int)g.w, 1);
        if (tid == 0) E = make_uint4(0x03020100u, 0x07060504u, 0x0B0A0908u, 0x0F0E0D0Cu);
        uint32_t e0 = E.x & 255u;
        uint32_t e1 = bsel16(f0, e0);
        uint32_t e2 = bsel16(f1, e1);
        uint32_t e3 = bsel16(f2, e2);
        entry_s[tid * 4 + 0] = (uint8_t)e0;
        entry_s[tid * 4 + 1] = (uint8_t)e1;
        entry_s[tid * 4 + 2] = (uint8_t)e2;
        entry_s[tid * 4 + 3] = (uint8_t)e3;
        uint32_t w0 = st16[(tid * 4 + 0) * 9 + (e0 >> 1)];
        uint32_t w1 = st16[(tid * 4 + 1) * 9 + (e1 >> 1)];
        uint32_t w2 = st16[(tid * 4 + 2) * 9 + (e2 >> 1)];
        uint32_t w3 = st16[(tid * 4 + 3) * 9 + (e3 >> 1)];
        int c0 = (int)(((w0 >> ((e0 & 1) * 16)) & 0xFFFFu) >> 8);
        int c1 = (int)(((w1 >> ((e1 & 1) * 16)) & 0xFFFFu) >> 8);
        int c2 = (int)(((w2 >> ((e2 & 1) * 16)) & 0xFFFFu) >> 8);
        int c3 = (int)(((w3 >> ((e3 & 1) * 16)) & 0xFFFFu) >> 8);
        int s = c0 + c1 + c2 + c3;
        int incl = s;
        #pragma unroll
        for (int d = 1; d < 64; d <<= 1) { int o = __shfl_up(incl, d); if (tid >= d) incl += o; }
        int excl = incl - s;
        pbase_s[tid * 4 + 0] = (uint16_t)excl;
        pbase_s[tid * 4 + 1] = (uint16_t)(excl + c0);
        pbase_s[tid * 4 + 2] = (uint16_t)(excl + c0 + c1);
        pbase_s[tid * 4 + 3] = (uint16_t)(excl + c0 + c1 + c2);
        if (tid == 63) S_s[0] = incl;    // total P
    }
    __syncthreads();                     // b4

    // ---- X: expand chunks via register walk + sentinel fill ----
    if (tid < NCH) {
        const int c = tid;
        const uint64_t W = (uint64_t)stopb[c] | ((uint64_t)stopb[c + 1] << 32);
        const int gb = c * 32;
        int pb = (int)pbase_s[c];
        int rel = (int)entry_s[c];
        while (rel < 32) {
            starts_s[pb++] = (uint16_t)(gb + rel);
            uint32_t win14 = (uint32_t)(W >> (rel + 2)) & 0x3FFFu;
            rel += win14 ? (2 + __builtin_ctz(win14)) : min(16, SEQ - (gb + rel));
        }
    }
    {
        const int P = S_s[0];
        for (int i = P + tid; i < 4098; i += NT) starts_s[i] = (uint16_t)SEQ;
    }
    __syncthreads();                     // b5

    // ---- G: emit this half; 4-lane groups, alignbit extraction; nt-stores ----
    {
        int* outp = out + (size_t)b * (MAXP * 16);
        int* outm = out + (size_t)NB * MAXP * 16 + (size_t)b * MAXP;
        const int j = tid & 3;
        #pragma unroll
        for (int it = 0; it < (MAXP / RED) / (NT / 4); ++it) {   // 8 passes
            const int p = qc * (MAXP / RED) + it * (NT / 4) + (tid >> 2);
            const int st = (int)starts_s[p];
            const int sz = (int)starts_s[p + 1] - st;            // 0..16 (0 when p>=P)
            const int base = (st >> 2) + j;
            const uint32_t sh = (uint32_t)(st & 3) * 8u;
            uint32_t lo = tok32[base], hi = tok32[base + 1];
            uint32_t pk = (uint32_t)((((uint64_t)hi << 32) | lo) >> sh);
            int rem = sz - 4 * j;
            rem = (rem < 0) ? 0 : (rem > 4 ? 4 : rem);
            pk &= (uint32_t)((1ULL << (8 * rem)) - 1ULL);
            i32x4 v = { (int)(pk & 255u), (int)((pk >> 8) & 255u),
                        (int)((pk >> 16) & 255u), (int)(pk >> 24) };
            __builtin_nontemporal_store(v, (i32x4*)outp + (size_t)p * 4 + j);
        }
        if (tid < (MAXP / RED) / 4) {    // masks: one int4 pass (512 threads)
            const int p4 = qc * (MAXP / RED) + tid * 4;
            const uint32_t* s32 = (const uint32_t*)starts_s;
            uint32_t a = s32[p4 >> 1], bw = s32[(p4 >> 1) + 1];
            i32x4 mv = { (a & 0xFFFFu) < SEQ ? 1 : 0, (a >> 16) < SEQ ? 1 : 0,
                         (bw & 0xFFFFu) < SEQ ? 1 : 0, (bw >> 16) < SEQ ? 1 : 0 };
            __builtin_nontemporal_store(mv, (i32x4*)(outm + qc * (MAXP / RED)) + tid);
        }
    }
}

extern "C" void kernel_launch(void* const* d_in, const int* in_sizes, int n_in,
                              void* d_out, int out_size, void* d_ws, size_t ws_size,
                              hipStream_t stream) {
    const int* tokens = (const int*)d_in[0];
    int* out = (int*)d_out;
    ep_fused<<<dim3(NB * RED), dim3(NT), 0, stream>>>(tokens, out);
}